// Round 5
// baseline (413.878 us; speedup 1.0000x reference)
//
#include <hip/hip_runtime.h>
#include <math.h>

#define AOFF 2097152   // recon = 32*64*1024 floats, alphas follow
#define LOFF 2359296   // AOFF + 32*8*1024

typedef __attribute__((ext_vector_type(8))) short short8;
typedef __attribute__((ext_vector_type(4))) float f32x4;

__device__ __forceinline__ int clsf(int v) { return v < 2 ? v : (v > 29 ? v - 27 : 2); }

__device__ __forceinline__ unsigned int f2bfu(float x) {
    unsigned int u = __float_as_uint(x);
    return (u + 0x7FFFu + ((u >> 16) & 1u)) >> 16;
}
__device__ __forceinline__ unsigned int cvt2(float a, float b) {
    return f2bfu(a) | (f2bfu(b) << 16);
}
__device__ __forceinline__ float bf2f(unsigned short u) {
    return __uint_as_float(((unsigned int)u) << 16);
}

// ---------------- w1 transpose: w1t[tap][i][o] ----------------
__global__ void w1t_kernel(const float* __restrict__ w1, float* __restrict__ w1t) {
    int idx = blockIdx.x * 256 + threadIdx.x;
    if (idx >= 204800) return;
    int tap = idx % 25, rest = idx / 25;       // rest = i*64+o
    w1t[tap * 8192 + rest] = w1[idx];
}

// ---------------- tapabc (abc fused): per-tap dot with affine pos coeffs ----------------
__global__ void tapabc_kernel(const float* __restrict__ pw, const float* __restrict__ pb,
                              const float* __restrict__ w1t, float* __restrict__ tapabc) {
    __shared__ float A3[384];
    int tap = blockIdx.x, t = threadIdx.x;     // 192 threads
    if (t < 128) {
        float p0 = pw[t * 4], p1 = pw[t * 4 + 1], p2 = pw[t * 4 + 2], p3 = pw[t * 4 + 3];
        A3[t] = p2 + p3 + pb[t];
        A3[128 + t] = p0 - p2;
        A3[256 + t] = p1 - p3;
    }
    __syncthreads();
    int o = t & 63, comp = t >> 6;
    const float* wp = w1t + tap * 8192 + o;
    const float* a = A3 + comp * 128;
    float s = 0.f;
    for (int i = 0; i < 128; ++i) s = fmaf(wp[i * 64], a[i], s);
    tapabc[(tap * 64 + o) * 3 + comp] = s;
}

// ---------------- P fill (clstab fused) ----------------
__global__ void pfill_kernel(const float* __restrict__ tapabc, const float* __restrict__ b1,
                             float* __restrict__ P) {
    __shared__ float uv[75];
    int o = blockIdx.x, t = threadIdx.x;       // 1024 threads
    if (t < 75) {
        int cls = t / 3, comp = t % 3;
        int cy = cls / 5, cx = cls % 5;
        const int klo[5] = {2, 1, 0, 0, 0}, khi[5] = {4, 4, 4, 3, 2};
        const float inv31 = 1.f / 31.f;
        float s = (comp == 0) ? b1[o] : 0.f;
        for (int ky = klo[cy]; ky <= khi[cy]; ++ky)
            for (int kx = klo[cx]; kx <= khi[cx]; ++kx) {
                int tap = (4 - ky) * 5 + (4 - kx);
                const float* tp = &tapabc[(tap * 64 + o) * 3];
                if (comp == 0) s += tp[0] + tp[1] * (ky - 2) * inv31 + tp[2] * (kx - 2) * inv31;
                else if (comp == 1) s += tp[1] * inv31;
                else s += tp[2] * inv31;
            }
        uv[t] = s;
    }
    __syncthreads();
    int y = t >> 5, x = t & 31;
    int cls = clsf(y) * 5 + clsf(x);
    P[(o << 10) + t] = uv[cls * 3] + uv[cls * 3 + 1] * y + uv[cls * 3 + 2] * x;
}

// ---------------- M (wsum+m fused, batched 8 latents/block) ----------------
__global__ void mlat_kernel(const float* __restrict__ latent, const float* __restrict__ w1t,
                            float* __restrict__ M) {
    __shared__ float ll[1024];
    __shared__ float T[12800];
    int nb = blockIdx.x * 8, t = threadIdx.x;
    for (int e = t; e < 1024; e += 256) ll[e] = latent[nb * 128 + e];
    __syncthreads();
    for (int e = t; e < 1600; e += 256) {
        int tap = e >> 6, o = e & 63;
        const float* wp = w1t + tap * 8192 + o;
        float s[8] = {0.f, 0.f, 0.f, 0.f, 0.f, 0.f, 0.f, 0.f};
        for (int i = 0; i < 128; ++i) {
            float wv = wp[i * 64];
            #pragma unroll
            for (int b = 0; b < 8; ++b) s[b] = fmaf(ll[b * 128 + i], wv, s[b]);
        }
        #pragma unroll
        for (int b = 0; b < 8; ++b) T[b * 1600 + e] = s[b];
    }
    __syncthreads();
    const int klo[5] = {2, 1, 0, 0, 0}, khi[5] = {4, 4, 4, 3, 2};
    for (int e = t; e < 12800; e += 256) {
        int b = e / 1600, r = e % 1600;
        int cls = r >> 6, o = r & 63;
        int cy = cls / 5, cx = cls % 5;
        float s = 0.f;
        for (int ky = klo[cy]; ky <= khi[cy]; ++ky)
            for (int kx = klo[cx]; kx <= khi[cx]; ++kx)
                s += T[b * 1600 + ((4 - ky) * 5 + (4 - kx)) * 64 + o];
        M[(nb + b) * 1600 + r] = s;
    }
}

// ---------------- merged weight prep (4 segments) ----------------
__global__ void prep_all_kernel(const float* __restrict__ a1w, const float* __restrict__ c1w,
                                const float* __restrict__ c2w, const float* __restrict__ ct2w,
                                short* __restrict__ wtall) {
    int gid = blockIdx.x * 256 + threadIdx.x;
    if (gid < 36864) {                                  // a1 / c1 : I=32,O=64
        const float* src = gid < 18432 ? a1w : c1w;
        int idx = gid < 18432 ? gid : gid - 18432;
        int j = idx & 7, fi = idx >> 3;
        int o = fi % 64, g = (fi / 64) & 3, t = fi / 256;
        int i = g * 8 + j;
        wtall[gid] = (short)f2bfu(src[(o * 32 + i) * 9 + (t / 3) * 3 + (t % 3)]);
    } else if (gid < 73728) {                           // c2 : I=64,O=64
        int idx = gid - 36864;
        int j = idx & 7, fi = idx >> 3;
        int o = fi % 64, g = (fi / 64) & 3, ks = (fi / 256) & 1, t = fi / 512;
        int i = ks * 32 + g * 8 + j;
        wtall[gid] = (short)f2bfu(c2w[(o * 64 + i) * 9 + (t / 3) * 3 + (t % 3)]);
    } else if (gid < 124928) {                          // convT2 : flipped 5x5
        int idx = gid - 73728;
        int j = idx & 7, fi = idx >> 3;
        int o = fi & 31, g = (fi >> 5) & 3, ks = (fi >> 7) & 1, t = fi >> 8;
        int i = ks * 32 + g * 8 + j;
        int ky = t / 5, kx = t % 5;
        wtall[gid] = (short)f2bfu(ct2w[((i * 32 + o) * 5 + (4 - ky)) * 5 + (4 - kx)]);
    }
}

// ---------------- conv5 (convT2): A from global, B row-cached, 2 barriers ----------------
__global__ __launch_bounds__(256) void conv5_kernel(
        const float* __restrict__ M, const float* __restrict__ P,
        const short* __restrict__ wt, const float* __restrict__ b2,
        float* __restrict__ feat) {
    constexpr int I = 64, XC = 36, ROWS = 12, MF = 2;
    __shared__ __align__(16) short tile[ROWS * XC * I];
    __shared__ float Ml[1600];
    const int n = blockIdx.x, y0 = blockIdx.y * 8;
    const int tid = threadIdx.x, w = tid >> 6, l = tid & 63;
    const int lx = l & 15, lg = l >> 4;

    for (int e = tid; e < 1600; e += 256) Ml[e] = M[n * 1600 + e];
    __syncthreads();
    for (int e = tid; e < ROWS * XC * 32; e += 256) {
        int cx = e % XC;
        int q = e / XC;
        int ip = q & 31;
        int r = q >> 5;
        int gy = y0 - 2 + r, gx = cx - 2;
        float v0 = 0.f, v1 = 0.f;
        if (gy >= 0 && gy < 32 && gx >= 0 && gx < 32) {
            int cls = clsf(gy) * 5 + clsf(gx);
            int pp = gy * 32 + gx;
            v0 = fmaxf(Ml[cls * 64 + 2 * ip]     + P[((2 * ip) << 10) + pp], 0.f);
            v1 = fmaxf(Ml[cls * 64 + 2 * ip + 1] + P[((2 * ip + 1) << 10) + pp], 0.f);
        }
        int off = ((r * XC + cx) * I + 2 * ip) * 2;
        off ^= (cx & 7) << 4;
        *(unsigned int*)((char*)tile + off) = cvt2(v0, v1);
    }
    __syncthreads();

    f32x4 acc[MF][2][2];
    #pragma unroll
    for (int m = 0; m < MF; ++m)
        #pragma unroll
        for (int q = 0; q < 2; ++q)
            #pragma unroll
            for (int c = 0; c < 2; ++c) acc[m][q][c] = (f32x4){0.f, 0.f, 0.f, 0.f};

    #pragma unroll 1
    for (int ks = 0; ks < 2; ++ks) {
        #pragma unroll 1
        for (int kx = 0; kx < 5; ++kx) {
            short8 af[5][MF];
            #pragma unroll
            for (int ky = 0; ky < 5; ++ky)
                #pragma unroll
                for (int m = 0; m < MF; ++m)
                    af[ky][m] = *(const short8*)(wt + (ky * 5 + kx) * 2048 +
                                                 ((ks * 4 + lg) * 32 + m * 16 + lx) * 8);
            const int key = ((kx + lx) & 7) << 4;
            #pragma unroll
            for (int colf = 0; colf < 2; ++colf) {
                const int cbase = ((2 * w) * XC + kx + colf * 16 + lx) * (I * 2)
                                + (ks * 32 + lg * 8) * 2;
                short8 bc[6];
                #pragma unroll
                for (int ir = 0; ir < 6; ++ir)
                    bc[ir] = *(const short8*)((char*)tile + ((cbase + ir * (XC * I * 2)) ^ key));
                #pragma unroll
                for (int ky = 0; ky < 5; ++ky)
                    #pragma unroll
                    for (int q = 0; q < 2; ++q)
                        #pragma unroll
                        for (int m = 0; m < MF; ++m)
                            acc[m][q][colf] = __builtin_amdgcn_mfma_f32_16x16x32_bf16(
                                af[ky][m], bc[q + ky], acc[m][q][colf], 0, 0, 0);
            }
        }
    }

    #pragma unroll
    for (int m = 0; m < MF; ++m)
        #pragma unroll
        for (int q = 0; q < 2; ++q)
            #pragma unroll
            for (int colf = 0; colf < 2; ++colf) {
                int yl = 2 * w + q, x = colf * 16 + lx;
                #pragma unroll
                for (int r = 0; r < 4; ++r) {
                    int och = m * 16 + lg * 4 + r;
                    float v = fmaxf(acc[m][q][colf][r] + b2[och], 0.f);
                    feat[(n * 32 + och) * 1024 + (y0 + yl) * 32 + x] = v;
                }
            }
}

// ---------------- conv3: A from global, B row-cached; optional fused a2-dot ----------------
template<int I, int O, int ACT, int INBF, int OUTBF, int FUSEA2>
__global__ __launch_bounds__(256) void conv3_kernel(
        const void* __restrict__ in_, const short* __restrict__ wt,
        const float* __restrict__ bias, void* __restrict__ out_,
        const float* __restrict__ a2w, float* __restrict__ s9) {
    constexpr int XC = 34, ROWS = 10, KS = I / 32, MF = O / 16, IH = I / 2;
    constexpr int TILE = ROWS * XC * I;
    constexpr int SMSZ = (FUSEA2 && TILE < 16384) ? 16384 : TILE;
    constexpr int ABUF = KS * 4 * O * 8;
    __shared__ __align__(16) short smem[SMSZ];
    __shared__ float wl[FUSEA2 ? 576 : 1];
    const int n = blockIdx.x, y0 = blockIdx.y * 8;
    const int tid = threadIdx.x, w = tid >> 6, l = tid & 63;
    const int lx = l & 15, lg = l >> 4;

    if constexpr (FUSEA2)
        for (int e = tid; e < 576; e += 256) wl[e] = a2w[e];

    for (int e = tid; e < ROWS * XC * IH; e += 256) {
        int cx = e % XC;
        int q = e / XC;
        int ip = q % IH;
        int r = q / IH;
        int gy = y0 - 1 + r, gx = cx - 1;
        unsigned int pack = 0u;
        if (gy >= 0 && gy < 32 && gx >= 0 && gx < 32) {
            if constexpr (INBF) {
                const unsigned short* p =
                    (const unsigned short*)in_ + (n * I + 2 * ip) * 1024 + gy * 32 + gx;
                pack = (unsigned int)p[0] | ((unsigned int)p[1024] << 16);
            } else {
                const float* p = (const float*)in_ + (n * I + 2 * ip) * 1024 + gy * 32 + gx;
                pack = cvt2(p[0], p[1024]);
            }
        }
        int off = ((r * XC + cx) * I + 2 * ip) * 2;
        off ^= (cx & 7) << 4;
        *(unsigned int*)((char*)smem + off) = pack;
    }
    __syncthreads();

    f32x4 acc[MF][2][2];
    #pragma unroll
    for (int m = 0; m < MF; ++m)
        #pragma unroll
        for (int q = 0; q < 2; ++q)
            #pragma unroll
            for (int c = 0; c < 2; ++c) acc[m][q][c] = (f32x4){0.f, 0.f, 0.f, 0.f};

    #pragma unroll 1
    for (int ks = 0; ks < KS; ++ks) {
        #pragma unroll 1
        for (int kx = 0; kx < 3; ++kx) {
            short8 af[3][MF];
            #pragma unroll
            for (int ky = 0; ky < 3; ++ky)
                #pragma unroll
                for (int m = 0; m < MF; ++m)
                    af[ky][m] = *(const short8*)(wt + (ky * 3 + kx) * ABUF +
                                                 ((ks * 4 + lg) * O + m * 16 + lx) * 8);
            const int key = ((kx + lx) & 7) << 4;
            #pragma unroll
            for (int colf = 0; colf < 2; ++colf) {
                const int cbase = ((2 * w) * XC + kx + colf * 16 + lx) * (I * 2)
                                + (ks * 32 + lg * 8) * 2;
                short8 bc[4];
                #pragma unroll
                for (int ir = 0; ir < 4; ++ir)
                    bc[ir] = *(const short8*)((char*)smem + ((cbase + ir * (XC * I * 2)) ^ key));
                #pragma unroll
                for (int ky = 0; ky < 3; ++ky)
                    #pragma unroll
                    for (int q = 0; q < 2; ++q)
                        #pragma unroll
                        for (int m = 0; m < MF; ++m)
                            acc[m][q][colf] = __builtin_amdgcn_mfma_f32_16x16x32_bf16(
                                af[ky][m], bc[q + ky], acc[m][q][colf], 0, 0, 0);
            }
        }
    }

    if constexpr (!FUSEA2) {
        #pragma unroll
        for (int m = 0; m < MF; ++m)
            #pragma unroll
            for (int q = 0; q < 2; ++q)
                #pragma unroll
                for (int colf = 0; colf < 2; ++colf) {
                    int yl = 2 * w + q, x = colf * 16 + lx;
                    #pragma unroll
                    for (int r = 0; r < 4; ++r) {
                        int och = m * 16 + lg * 4 + r;
                        float v = acc[m][q][colf][r] + bias[och];
                        if (ACT == 1) v = v / (1.f + expf(-v));
                        int oidx = (n * O + och) * 1024 + (y0 + yl) * 32 + x;
                        if constexpr (OUTBF)
                            ((unsigned short*)out_)[oidx] = (unsigned short)f2bfu(v);
                        else
                            ((float*)out_)[oidx] = v;
                    }
                }
    } else {
        __syncthreads();
        // write silu(a1) to smem as bf16 [px_lin(256)][ch(64)], swizzled
        #pragma unroll
        for (int m = 0; m < MF; ++m)
            #pragma unroll
            for (int q = 0; q < 2; ++q)
                #pragma unroll
                for (int colf = 0; colf < 2; ++colf) {
                    int px_lin = (2 * w + q) * 32 + colf * 16 + lx;
                    unsigned long long pk = 0ull;
                    #pragma unroll
                    for (int r = 0; r < 4; ++r) {
                        int och = m * 16 + lg * 4 + r;
                        float v = acc[m][q][colf][r] + bias[och];
                        v = v / (1.f + expf(-v));
                        pk |= (unsigned long long)f2bfu(v) << (16 * r);
                    }
                    int off = (px_lin * 64 + m * 16 + lg * 4) * 2;
                    off ^= (px_lin & 7) << 4;
                    *(unsigned long long*)((char*)smem + off) = pk;
                }
        __syncthreads();
        float a1v[64];
        {
            const int key2 = (tid & 7) << 4;
            #pragma unroll
            for (int c = 0; c < 8; ++c) {
                short8 v = *(const short8*)((char*)smem + (((tid * 64 + c * 8) * 2) ^ key2));
                #pragma unroll
                for (int j = 0; j < 8; ++j) a1v[c * 8 + j] = bf2f((unsigned short)v[j]);
            }
        }
        int rr = tid >> 5, x = tid & 31;
        #pragma unroll 1
        for (int tap = 0; tap < 9; ++tap) {
            float s = 0.f;
            #pragma unroll
            for (int ch = 0; ch < 64; ++ch) s = fmaf(a1v[ch], wl[ch * 9 + tap], s);
            s9[(tap << 18) + (n << 10) + (y0 + rr) * 32 + x] = s;
        }
    }
}

// ---------------- a2 tap-sum + slot softmax ----------------
__global__ void a2soft_kernel(const float* __restrict__ s9, const float* __restrict__ b2,
                              float* __restrict__ outp) {
    int idx = blockIdx.x * 256 + threadIdx.x;
    if (idx >= 32 * 1024) return;
    int bb = idx >> 10, yx = idx & 1023;
    int y = yx >> 5, x = yx & 31;
    float v[8];
    float bias = b2[0];
    #pragma unroll
    for (int s = 0; s < 8; ++s) {
        int n = bb * 8 + s;
        float a = bias;
        #pragma unroll
        for (int ky = 0; ky < 3; ++ky) {
            int yy = y + ky - 1;
            if (yy < 0 || yy > 31) continue;
            #pragma unroll
            for (int kx = 0; kx < 3; ++kx) {
                int xx = x + kx - 1;
                if (xx < 0 || xx > 31) continue;
                a += s9[((ky * 3 + kx) << 18) + (n << 10) + yy * 32 + xx];
            }
        }
        v[s] = a;
    }
    float m = -3.4e38f;
    #pragma unroll
    for (int s = 0; s < 8; ++s) m = fmaxf(m, v[s]);
    float sum = 0.f;
    #pragma unroll
    for (int s = 0; s < 8; ++s) { v[s] = expf(v[s] - m); sum += v[s]; }
    float inv = 1.f / sum;
    #pragma unroll
    for (int s = 0; s < 8; ++s) outp[AOFF + ((bb * 8 + s) << 10) + yx] = v[s] * inv;
}

// ---------------- VQ ----------------
__global__ void vq_kernel(const float* __restrict__ feat, const float* __restrict__ codebook,
                          unsigned short* __restrict__ qfeat, float* __restrict__ partial) {
    __shared__ float cb[4096];
    __shared__ float cn[128];
    __shared__ float wsumr[4];
    int t = threadIdx.x;
    for (int e = t; e < 4096; e += 256) cb[e] = codebook[e];
    __syncthreads();
    if (t < 128) {
        float s = 0.f;
        #pragma unroll
        for (int c = 0; c < 32; ++c) { float v = cb[t * 32 + c]; s = fmaf(v, v, s); }
        cn[t] = s;
    }
    __syncthreads();
    int idx = blockIdx.x * 256 + t;
    int n = idx >> 10, yx = idx & 1023;
    float f[32];
    #pragma unroll
    for (int c = 0; c < 32; ++c) f[c] = feat[(n * 32 + c) * 1024 + yx];
    float best = 3.4e38f; int bi = 0;
    for (int k = 0; k < 128; ++k) {
        const float* cp = &cb[k * 32];
        float d0 = 0.f, d1 = 0.f, d2 = 0.f, d3 = 0.f;
        #pragma unroll
        for (int c = 0; c < 32; c += 4) {
            d0 = fmaf(f[c], cp[c], d0);
            d1 = fmaf(f[c + 1], cp[c + 1], d1);
            d2 = fmaf(f[c + 2], cp[c + 2], d2);
            d3 = fmaf(f[c + 3], cp[c + 3], d3);
        }
        float d = cn[k] - 2.f * ((d0 + d1) + (d2 + d3));
        if (d < best) { best = d; bi = k; }
    }
    float lsum = 0.f;
    const float* q = &cb[bi * 32];
    #pragma unroll
    for (int c = 0; c < 32; ++c) {
        float qv = q[c];
        qfeat[(n * 32 + c) * 1024 + yx] = (unsigned short)f2bfu(qv);
        float dd = qv - f[c];
        lsum = fmaf(dd, dd, lsum);
    }
    for (int off = 32; off > 0; off >>= 1) lsum += __shfl_down(lsum, off);
    int lane = t & 63, wid = t >> 6;
    if (lane == 0) wsumr[wid] = lsum;
    __syncthreads();
    if (t == 0) partial[blockIdx.x] = (wsumr[0] + wsumr[1]) + (wsumr[2] + wsumr[3]);
}

__global__ void recon_kernel(const unsigned short* __restrict__ colors, float* __restrict__ outp) {
    int idx = blockIdx.x * 256 + threadIdx.x;
    int yx = idx & 1023;
    int v = (idx >> 10) & 63;
    int bb = idx >> 16;
    float acc = 0.f;
    #pragma unroll
    for (int s = 0; s < 8; ++s) {
        float a = outp[AOFF + ((bb * 8 + s) << 10) + yx];
        float c = bf2f(colors[((bb * 8 + s) * 64 + v) * 1024 + yx]);
        acc = fmaf(a, c, acc);
    }
    outp[idx] = acc;
}

__global__ void loss_kernel(const float* __restrict__ partial, float* __restrict__ outp) {
    __shared__ float red[4];
    int t = threadIdx.x;
    float s = 0.f;
    for (int i = t; i < 1024; i += 256) s += partial[i];
    for (int o = 32; o > 0; o >>= 1) s += __shfl_down(s, o);
    if ((t & 63) == 0) red[t >> 6] = s;
    __syncthreads();
    if (t == 0) outp[LOFF] = 1.25f * ((red[0] + red[1]) + (red[2] + red[3])) / 8388608.0f;
}

extern "C" void kernel_launch(void* const* d_in, const int* in_sizes, int n_in,
                              void* d_out, int out_size, void* d_ws, size_t ws_size,
                              hipStream_t stream) {
    const float* latent  = (const float*)d_in[0];
    const float* pos_w   = (const float*)d_in[1];
    const float* pos_b   = (const float*)d_in[2];
    const float* ct1_w   = (const float*)d_in[3];
    const float* ct1_b   = (const float*)d_in[4];
    const float* ct2_w   = (const float*)d_in[5];
    const float* ct2_b   = (const float*)d_in[6];
    const float* codebook= (const float*)d_in[7];
    const float* c1_w    = (const float*)d_in[8];
    const float* c1_b    = (const float*)d_in[9];
    const float* c2_w    = (const float*)d_in[10];
    const float* c2_b    = (const float*)d_in[11];
    const float* a1_w    = (const float*)d_in[12];
    const float* a1_b    = (const float*)d_in[13];
    const float* a2_w    = (const float*)d_in[14];
    const float* a2_b    = (const float*)d_in[15];
    float* out = (float*)d_out;

    float* ws     = (float*)d_ws;
    float* feat   = ws;                      // 8388608
    float* s9     = feat + 8388608;          // 2359296
    float* tapabc = s9 + 2359296;            // 4800
    float* P      = tapabc + 4800;           // 65536
    float* M      = P + 65536;               // 409600
    float* partial= M + 409600;              // 1024
    float* w1t    = partial + 1024;          // 204800
    short* wtall  = (short*)(w1t + 204800);  // 124928 shorts
    short* wtA    = wtall;
    short* wtC1   = wtall + 18432;
    short* wtC2   = wtall + 36864;
    short* wtT2   = wtall + 73728;
    unsigned short* tmpb    = (unsigned short*)(wtall + 124928);  // 16777216
    unsigned short* qfeatb  = tmpb + 16777216;                    // 8388608
    unsigned short* colorsb = qfeatb + 8388608;                   // 16777216

    w1t_kernel<<<800, 256, 0, stream>>>(ct1_w, w1t);
    tapabc_kernel<<<25, 192, 0, stream>>>(pos_w, pos_b, w1t, tapabc);
    pfill_kernel<<<64, 1024, 0, stream>>>(tapabc, ct1_b, P);
    mlat_kernel<<<32, 256, 0, stream>>>(latent, w1t, M);
    prep_all_kernel<<<488, 256, 0, stream>>>(a1_w, c1_w, c2_w, ct2_w, wtall);

    conv5_kernel<<<dim3(256, 4), 256, 0, stream>>>(M, P, wtT2, ct2_b, feat);
    // alpha head: a1 conv with fused a2 channel-dot -> s9 -> softmax
    conv3_kernel<32, 64, 1, 0, 0, 1><<<dim3(256, 4), 256, 0, stream>>>(
        feat, wtA, a1_b, nullptr, a2_w, s9);
    a2soft_kernel<<<128, 256, 0, stream>>>(s9, a2_b, out);
    // VQ
    vq_kernel<<<1024, 256, 0, stream>>>(feat, codebook, qfeatb, partial);
    // color head
    conv3_kernel<32, 64, 1, 1, 1, 0><<<dim3(256, 4), 256, 0, stream>>>(
        qfeatb, wtC1, c1_b, tmpb, nullptr, nullptr);
    conv3_kernel<64, 64, 0, 1, 1, 0><<<dim3(256, 4), 256, 0, stream>>>(
        tmpb, wtC2, c2_b, colorsb, nullptr, nullptr);
    recon_kernel<<<8192, 256, 0, stream>>>(colorsb, out);
    loss_kernel<<<1, 256, 0, stream>>>(partial, out);
}

// Round 6
// 337.864 us; speedup vs baseline: 1.2250x; 1.2250x over previous
//
#include <hip/hip_runtime.h>
#include <math.h>

#define AOFF 2097152   // recon = 32*64*1024 floats, alphas follow
#define LOFF 2359296   // AOFF + 32*8*1024

typedef __attribute__((ext_vector_type(8))) short short8;
typedef __attribute__((ext_vector_type(4))) float f32x4;

__device__ __forceinline__ int clsf(int v) { return v < 2 ? v : (v > 29 ? v - 27 : 2); }

__device__ __forceinline__ unsigned int f2bfu(float x) {
    unsigned int u = __float_as_uint(x);
    return (u + 0x7FFFu + ((u >> 16) & 1u)) >> 16;
}
__device__ __forceinline__ unsigned int cvt2(float a, float b) {
    return f2bfu(a) | (f2bfu(b) << 16);
}
__device__ __forceinline__ float bf2f(unsigned short u) {
    return __uint_as_float(((unsigned int)u) << 16);
}

// ---------------- w1 transpose: w1t[tap][i][o] ----------------
__global__ void w1t_kernel(const float* __restrict__ w1, float* __restrict__ w1t) {
    int idx = blockIdx.x * 256 + threadIdx.x;
    if (idx >= 204800) return;
    int tap = idx % 25, rest = idx / 25;       // rest = i*64+o
    w1t[tap * 8192 + rest] = w1[idx];
}

// ---------------- tapabc: per-tap dot with affine pos coeffs ----------------
__global__ void tapabc_kernel(const float* __restrict__ pw, const float* __restrict__ pb,
                              const float* __restrict__ w1t, float* __restrict__ tapabc) {
    __shared__ float A3[384];
    int tap = blockIdx.x, t = threadIdx.x;     // 192 threads
    if (t < 128) {
        float p0 = pw[t * 4], p1 = pw[t * 4 + 1], p2 = pw[t * 4 + 2], p3 = pw[t * 4 + 3];
        A3[t] = p2 + p3 + pb[t];
        A3[128 + t] = p0 - p2;
        A3[256 + t] = p1 - p3;
    }
    __syncthreads();
    int o = t & 63, comp = t >> 6;
    const float* wp = w1t + tap * 8192 + o;
    const float* a = A3 + comp * 128;
    float s = 0.f;
    for (int i = 0; i < 128; ++i) s = fmaf(wp[i * 64], a[i], s);
    tapabc[(tap * 64 + o) * 3 + comp] = s;
}

// ---------------- P fill ----------------
__global__ void pfill_kernel(const float* __restrict__ tapabc, const float* __restrict__ b1,
                             float* __restrict__ P) {
    __shared__ float uv[75];
    int o = blockIdx.x, t = threadIdx.x;       // 1024 threads
    if (t < 75) {
        int cls = t / 3, comp = t % 3;
        int cy = cls / 5, cx = cls % 5;
        const int klo[5] = {2, 1, 0, 0, 0}, khi[5] = {4, 4, 4, 3, 2};
        const float inv31 = 1.f / 31.f;
        float s = (comp == 0) ? b1[o] : 0.f;
        for (int ky = klo[cy]; ky <= khi[cy]; ++ky)
            for (int kx = klo[cx]; kx <= khi[cx]; ++kx) {
                int tap = (4 - ky) * 5 + (4 - kx);
                const float* tp = &tapabc[(tap * 64 + o) * 3];
                if (comp == 0) s += tp[0] + tp[1] * (ky - 2) * inv31 + tp[2] * (kx - 2) * inv31;
                else if (comp == 1) s += tp[1] * inv31;
                else s += tp[2] * inv31;
            }
        uv[t] = s;
    }
    __syncthreads();
    int y = t >> 5, x = t & 31;
    int cls = clsf(y) * 5 + clsf(x);
    P[(o << 10) + t] = uv[cls * 3] + uv[cls * 3 + 1] * y + uv[cls * 3 + 2] * x;
}

// ---------------- Wsum[cls][i][o] (parallel, R4-proven) ----------------
__global__ void wsum_kernel(const float* __restrict__ w1, float* __restrict__ Wsum) {
    int idx = blockIdx.x * 256 + threadIdx.x;
    if (idx >= 25 * 128 * 64) return;
    int cls = idx >> 13;
    int i = (idx >> 6) & 127;
    int o = idx & 63;
    int cy = cls / 5, cx = cls % 5;
    const int klo[5] = {2, 1, 0, 0, 0}, khi[5] = {4, 4, 4, 3, 2};
    float s = 0.f;
    for (int ky = klo[cy]; ky <= khi[cy]; ++ky)
        for (int kx = klo[cx]; kx <= khi[cx]; ++kx)
            s += w1[(i * 64 + o) * 25 + (4 - ky) * 5 + (4 - kx)];
    Wsum[idx] = s;
}

// ---------------- M[n][cls][o] = latent[n,:] . Wsum[cls,:,o] ----------------
__global__ void m_kernel(const float* __restrict__ latent, const float* __restrict__ Wsum,
                         float* __restrict__ M) {
    int n = blockIdx.x, cls = blockIdx.y, o = threadIdx.x;
    const float* l = &latent[n * 128];
    const float* w = &Wsum[cls * 8192 + o];
    float a0 = 0.f, a1 = 0.f;
    for (int i = 0; i < 128; i += 2) {
        a0 = fmaf(l[i], w[i * 64], a0);
        a1 = fmaf(l[i + 1], w[(i + 1) * 64], a1);
    }
    M[(n * 25 + cls) * 64 + o] = a0 + a1;
}

// ---------------- merged weight prep (4 segments) ----------------
__global__ void prep_all_kernel(const float* __restrict__ a1w, const float* __restrict__ c1w,
                                const float* __restrict__ c2w, const float* __restrict__ ct2w,
                                short* __restrict__ wtall) {
    int gid = blockIdx.x * 256 + threadIdx.x;
    if (gid < 36864) {                                  // a1 / c1 : I=32,O=64
        const float* src = gid < 18432 ? a1w : c1w;
        int idx = gid < 18432 ? gid : gid - 18432;
        int j = idx & 7, fi = idx >> 3;
        int o = fi % 64, g = (fi / 64) & 3, t = fi / 256;
        int i = g * 8 + j;
        wtall[gid] = (short)f2bfu(src[(o * 32 + i) * 9 + (t / 3) * 3 + (t % 3)]);
    } else if (gid < 73728) {                           // c2 : I=64,O=64
        int idx = gid - 36864;
        int j = idx & 7, fi = idx >> 3;
        int o = fi % 64, g = (fi / 64) & 3, ks = (fi / 256) & 1, t = fi / 512;
        int i = ks * 32 + g * 8 + j;
        wtall[gid] = (short)f2bfu(c2w[(o * 64 + i) * 9 + (t / 3) * 3 + (t % 3)]);
    } else if (gid < 124928) {                          // convT2 : flipped 5x5
        int idx = gid - 73728;
        int j = idx & 7, fi = idx >> 3;
        int o = fi & 31, g = (fi >> 5) & 3, ks = (fi >> 7) & 1, t = fi >> 8;
        int i = ks * 32 + g * 8 + j;
        int ky = t / 5, kx = t % 5;
        wtall[gid] = (short)f2bfu(ct2w[((i * 32 + o) * 5 + (4 - ky)) * 5 + (4 - kx)]);
    }
}

// ---------------- conv5 (convT2): A from global, B row-cached, 2 barriers ----------------
__global__ __launch_bounds__(256) void conv5_kernel(
        const float* __restrict__ M, const float* __restrict__ P,
        const short* __restrict__ wt, const float* __restrict__ b2,
        float* __restrict__ feat) {
    constexpr int I = 64, XC = 36, ROWS = 12, MF = 2;
    __shared__ __align__(16) short tile[ROWS * XC * I];
    __shared__ float Ml[1600];
    const int n = blockIdx.x, y0 = blockIdx.y * 8;
    const int tid = threadIdx.x, w = tid >> 6, l = tid & 63;
    const int lx = l & 15, lg = l >> 4;

    for (int e = tid; e < 1600; e += 256) Ml[e] = M[n * 1600 + e];
    __syncthreads();
    for (int e = tid; e < ROWS * XC * 32; e += 256) {
        int cx = e % XC;
        int q = e / XC;
        int ip = q & 31;
        int r = q >> 5;
        int gy = y0 - 2 + r, gx = cx - 2;
        float v0 = 0.f, v1 = 0.f;
        if (gy >= 0 && gy < 32 && gx >= 0 && gx < 32) {
            int cls = clsf(gy) * 5 + clsf(gx);
            int pp = gy * 32 + gx;
            v0 = fmaxf(Ml[cls * 64 + 2 * ip]     + P[((2 * ip) << 10) + pp], 0.f);
            v1 = fmaxf(Ml[cls * 64 + 2 * ip + 1] + P[((2 * ip + 1) << 10) + pp], 0.f);
        }
        int off = ((r * XC + cx) * I + 2 * ip) * 2;
        off ^= (cx & 7) << 4;
        *(unsigned int*)((char*)tile + off) = cvt2(v0, v1);
    }
    __syncthreads();

    f32x4 acc[MF][2][2];
    #pragma unroll
    for (int m = 0; m < MF; ++m)
        #pragma unroll
        for (int q = 0; q < 2; ++q)
            #pragma unroll
            for (int c = 0; c < 2; ++c) acc[m][q][c] = (f32x4){0.f, 0.f, 0.f, 0.f};

    #pragma unroll 1
    for (int ks = 0; ks < 2; ++ks) {
        #pragma unroll 1
        for (int kx = 0; kx < 5; ++kx) {
            short8 af[5][MF];
            #pragma unroll
            for (int ky = 0; ky < 5; ++ky)
                #pragma unroll
                for (int m = 0; m < MF; ++m)
                    af[ky][m] = *(const short8*)(wt + (ky * 5 + kx) * 2048 +
                                                 ((ks * 4 + lg) * 32 + m * 16 + lx) * 8);
            const int key = ((kx + lx) & 7) << 4;
            #pragma unroll
            for (int colf = 0; colf < 2; ++colf) {
                const int cbase = ((2 * w) * XC + kx + colf * 16 + lx) * (I * 2)
                                + (ks * 32 + lg * 8) * 2;
                short8 bc[6];
                #pragma unroll
                for (int ir = 0; ir < 6; ++ir)
                    bc[ir] = *(const short8*)((char*)tile + ((cbase + ir * (XC * I * 2)) ^ key));
                #pragma unroll
                for (int ky = 0; ky < 5; ++ky)
                    #pragma unroll
                    for (int q = 0; q < 2; ++q)
                        #pragma unroll
                        for (int m = 0; m < MF; ++m)
                            acc[m][q][colf] = __builtin_amdgcn_mfma_f32_16x16x32_bf16(
                                af[ky][m], bc[q + ky], acc[m][q][colf], 0, 0, 0);
            }
        }
    }

    #pragma unroll
    for (int m = 0; m < MF; ++m)
        #pragma unroll
        for (int q = 0; q < 2; ++q)
            #pragma unroll
            for (int colf = 0; colf < 2; ++colf) {
                int yl = 2 * w + q, x = colf * 16 + lx;
                #pragma unroll
                for (int r = 0; r < 4; ++r) {
                    int och = m * 16 + lg * 4 + r;
                    float v = fmaxf(acc[m][q][colf][r] + b2[och], 0.f);
                    feat[(n * 32 + och) * 1024 + (y0 + yl) * 32 + x] = v;
                }
            }
}

// ---------------- conv3: A from global, B row-cached; optional fused a2-dot ----------------
template<int I, int O, int ACT, int INBF, int OUTBF, int FUSEA2>
__global__ __launch_bounds__(256) void conv3_kernel(
        const void* __restrict__ in_, const short* __restrict__ wt,
        const float* __restrict__ bias, void* __restrict__ out_,
        const float* __restrict__ a2w, float* __restrict__ s9) {
    constexpr int XC = 34, ROWS = 10, KS = I / 32, MF = O / 16, IH = I / 2;
    constexpr int TILE = ROWS * XC * I;
    constexpr int SMSZ = (FUSEA2 && TILE < 16384) ? 16384 : TILE;
    constexpr int ABUF = KS * 4 * O * 8;
    __shared__ __align__(16) short smem[SMSZ];
    __shared__ float wl[FUSEA2 ? 576 : 1];
    const int n = blockIdx.x, y0 = blockIdx.y * 8;
    const int tid = threadIdx.x, w = tid >> 6, l = tid & 63;
    const int lx = l & 15, lg = l >> 4;

    if constexpr (FUSEA2)
        for (int e = tid; e < 576; e += 256) wl[e] = a2w[e];

    for (int e = tid; e < ROWS * XC * IH; e += 256) {
        int cx = e % XC;
        int q = e / XC;
        int ip = q % IH;
        int r = q / IH;
        int gy = y0 - 1 + r, gx = cx - 1;
        unsigned int pack = 0u;
        if (gy >= 0 && gy < 32 && gx >= 0 && gx < 32) {
            if constexpr (INBF) {
                const unsigned short* p =
                    (const unsigned short*)in_ + (n * I + 2 * ip) * 1024 + gy * 32 + gx;
                pack = (unsigned int)p[0] | ((unsigned int)p[1024] << 16);
            } else {
                const float* p = (const float*)in_ + (n * I + 2 * ip) * 1024 + gy * 32 + gx;
                pack = cvt2(p[0], p[1024]);
            }
        }
        int off = ((r * XC + cx) * I + 2 * ip) * 2;
        off ^= (cx & 7) << 4;
        *(unsigned int*)((char*)smem + off) = pack;
    }
    __syncthreads();

    f32x4 acc[MF][2][2];
    #pragma unroll
    for (int m = 0; m < MF; ++m)
        #pragma unroll
        for (int q = 0; q < 2; ++q)
            #pragma unroll
            for (int c = 0; c < 2; ++c) acc[m][q][c] = (f32x4){0.f, 0.f, 0.f, 0.f};

    #pragma unroll 1
    for (int ks = 0; ks < KS; ++ks) {
        #pragma unroll 1
        for (int kx = 0; kx < 3; ++kx) {
            short8 af[3][MF];
            #pragma unroll
            for (int ky = 0; ky < 3; ++ky)
                #pragma unroll
                for (int m = 0; m < MF; ++m)
                    af[ky][m] = *(const short8*)(wt + (ky * 3 + kx) * ABUF +
                                                 ((ks * 4 + lg) * O + m * 16 + lx) * 8);
            const int key = ((kx + lx) & 7) << 4;
            #pragma unroll
            for (int colf = 0; colf < 2; ++colf) {
                const int cbase = ((2 * w) * XC + kx + colf * 16 + lx) * (I * 2)
                                + (ks * 32 + lg * 8) * 2;
                short8 bc[4];
                #pragma unroll
                for (int ir = 0; ir < 4; ++ir)
                    bc[ir] = *(const short8*)((char*)smem + ((cbase + ir * (XC * I * 2)) ^ key));
                #pragma unroll
                for (int ky = 0; ky < 3; ++ky)
                    #pragma unroll
                    for (int q = 0; q < 2; ++q)
                        #pragma unroll
                        for (int m = 0; m < MF; ++m)
                            acc[m][q][colf] = __builtin_amdgcn_mfma_f32_16x16x32_bf16(
                                af[ky][m], bc[q + ky], acc[m][q][colf], 0, 0, 0);
            }
        }
    }

    if constexpr (!FUSEA2) {
        #pragma unroll
        for (int m = 0; m < MF; ++m)
            #pragma unroll
            for (int q = 0; q < 2; ++q)
                #pragma unroll
                for (int colf = 0; colf < 2; ++colf) {
                    int yl = 2 * w + q, x = colf * 16 + lx;
                    #pragma unroll
                    for (int r = 0; r < 4; ++r) {
                        int och = m * 16 + lg * 4 + r;
                        float v = acc[m][q][colf][r] + bias[och];
                        if (ACT == 1) v = v / (1.f + expf(-v));
                        int oidx = (n * O + och) * 1024 + (y0 + yl) * 32 + x;
                        if constexpr (OUTBF)
                            ((unsigned short*)out_)[oidx] = (unsigned short)f2bfu(v);
                        else
                            ((float*)out_)[oidx] = v;
                    }
                }
    } else {
        __syncthreads();
        // write silu(a1) to smem as bf16 [px_lin(256)][ch(64)], swizzled
        #pragma unroll
        for (int m = 0; m < MF; ++m)
            #pragma unroll
            for (int q = 0; q < 2; ++q)
                #pragma unroll
                for (int colf = 0; colf < 2; ++colf) {
                    int px_lin = (2 * w + q) * 32 + colf * 16 + lx;
                    unsigned long long pk = 0ull;
                    #pragma unroll
                    for (int r = 0; r < 4; ++r) {
                        int och = m * 16 + lg * 4 + r;
                        float v = acc[m][q][colf][r] + bias[och];
                        v = v / (1.f + expf(-v));
                        pk |= (unsigned long long)f2bfu(v) << (16 * r);
                    }
                    int off = (px_lin * 64 + m * 16 + lg * 4) * 2;
                    off ^= (px_lin & 7) << 4;
                    *(unsigned long long*)((char*)smem + off) = pk;
                }
        __syncthreads();
        float a1v[64];
        {
            const int key2 = (tid & 7) << 4;
            #pragma unroll
            for (int c = 0; c < 8; ++c) {
                short8 v = *(const short8*)((char*)smem + (((tid * 64 + c * 8) * 2) ^ key2));
                #pragma unroll
                for (int j = 0; j < 8; ++j) a1v[c * 8 + j] = bf2f((unsigned short)v[j]);
            }
        }
        int rr = tid >> 5, x = tid & 31;
        #pragma unroll 1
        for (int tap = 0; tap < 9; ++tap) {
            float s = 0.f;
            #pragma unroll
            for (int ch = 0; ch < 64; ++ch) s = fmaf(a1v[ch], wl[ch * 9 + tap], s);
            s9[(tap << 18) + (n << 10) + (y0 + rr) * 32 + x] = s;
        }
    }
}

// ---------------- a2 tap-sum + slot softmax ----------------
__global__ void a2soft_kernel(const float* __restrict__ s9, const float* __restrict__ b2,
                              float* __restrict__ outp) {
    int idx = blockIdx.x * 256 + threadIdx.x;
    if (idx >= 32 * 1024) return;
    int bb = idx >> 10, yx = idx & 1023;
    int y = yx >> 5, x = yx & 31;
    float v[8];
    float bias = b2[0];
    #pragma unroll
    for (int s = 0; s < 8; ++s) {
        int n = bb * 8 + s;
        float a = bias;
        #pragma unroll
        for (int ky = 0; ky < 3; ++ky) {
            int yy = y + ky - 1;
            if (yy < 0 || yy > 31) continue;
            #pragma unroll
            for (int kx = 0; kx < 3; ++kx) {
                int xx = x + kx - 1;
                if (xx < 0 || xx > 31) continue;
                a += s9[((ky * 3 + kx) << 18) + (n << 10) + yy * 32 + xx];
            }
        }
        v[s] = a;
    }
    float m = -3.4e38f;
    #pragma unroll
    for (int s = 0; s < 8; ++s) m = fmaxf(m, v[s]);
    float sum = 0.f;
    #pragma unroll
    for (int s = 0; s < 8; ++s) { v[s] = expf(v[s] - m); sum += v[s]; }
    float inv = 1.f / sum;
    #pragma unroll
    for (int s = 0; s < 8; ++s) outp[AOFF + ((bb * 8 + s) << 10) + yx] = v[s] * inv;
}

// ---------------- VQ ----------------
__global__ void vq_kernel(const float* __restrict__ feat, const float* __restrict__ codebook,
                          unsigned short* __restrict__ qfeat, float* __restrict__ partial) {
    __shared__ float cb[4096];
    __shared__ float cn[128];
    __shared__ float wsumr[4];
    int t = threadIdx.x;
    for (int e = t; e < 4096; e += 256) cb[e] = codebook[e];
    __syncthreads();
    if (t < 128) {
        float s = 0.f;
        #pragma unroll
        for (int c = 0; c < 32; ++c) { float v = cb[t * 32 + c]; s = fmaf(v, v, s); }
        cn[t] = s;
    }
    __syncthreads();
    int idx = blockIdx.x * 256 + t;
    int n = idx >> 10, yx = idx & 1023;
    float f[32];
    #pragma unroll
    for (int c = 0; c < 32; ++c) f[c] = feat[(n * 32 + c) * 1024 + yx];
    float best = 3.4e38f; int bi = 0;
    for (int k = 0; k < 128; ++k) {
        const float* cp = &cb[k * 32];
        float d0 = 0.f, d1 = 0.f, d2 = 0.f, d3 = 0.f;
        #pragma unroll
        for (int c = 0; c < 32; c += 4) {
            d0 = fmaf(f[c], cp[c], d0);
            d1 = fmaf(f[c + 1], cp[c + 1], d1);
            d2 = fmaf(f[c + 2], cp[c + 2], d2);
            d3 = fmaf(f[c + 3], cp[c + 3], d3);
        }
        float d = cn[k] - 2.f * ((d0 + d1) + (d2 + d3));
        if (d < best) { best = d; bi = k; }
    }
    float lsum = 0.f;
    const float* q = &cb[bi * 32];
    #pragma unroll
    for (int c = 0; c < 32; ++c) {
        float qv = q[c];
        qfeat[(n * 32 + c) * 1024 + yx] = (unsigned short)f2bfu(qv);
        float dd = qv - f[c];
        lsum = fmaf(dd, dd, lsum);
    }
    for (int off = 32; off > 0; off >>= 1) lsum += __shfl_down(lsum, off);
    int lane = t & 63, wid = t >> 6;
    if (lane == 0) wsumr[wid] = lsum;
    __syncthreads();
    if (t == 0) partial[blockIdx.x] = (wsumr[0] + wsumr[1]) + (wsumr[2] + wsumr[3]);
}

__global__ void recon_kernel(const unsigned short* __restrict__ colors, float* __restrict__ outp) {
    int idx = blockIdx.x * 256 + threadIdx.x;
    int yx = idx & 1023;
    int v = (idx >> 10) & 63;
    int bb = idx >> 16;
    float acc = 0.f;
    #pragma unroll
    for (int s = 0; s < 8; ++s) {
        float a = outp[AOFF + ((bb * 8 + s) << 10) + yx];
        float c = bf2f(colors[((bb * 8 + s) * 64 + v) * 1024 + yx]);
        acc = fmaf(a, c, acc);
    }
    outp[idx] = acc;
}

__global__ void loss_kernel(const float* __restrict__ partial, float* __restrict__ outp) {
    __shared__ float red[4];
    int t = threadIdx.x;
    float s = 0.f;
    for (int i = t; i < 1024; i += 256) s += partial[i];
    for (int o = 32; o > 0; o >>= 1) s += __shfl_down(s, o);
    if ((t & 63) == 0) red[t >> 6] = s;
    __syncthreads();
    if (t == 0) outp[LOFF] = 1.25f * ((red[0] + red[1]) + (red[2] + red[3])) / 8388608.0f;
}

extern "C" void kernel_launch(void* const* d_in, const int* in_sizes, int n_in,
                              void* d_out, int out_size, void* d_ws, size_t ws_size,
                              hipStream_t stream) {
    const float* latent  = (const float*)d_in[0];
    const float* pos_w   = (const float*)d_in[1];
    const float* pos_b   = (const float*)d_in[2];
    const float* ct1_w   = (const float*)d_in[3];
    const float* ct1_b   = (const float*)d_in[4];
    const float* ct2_w   = (const float*)d_in[5];
    const float* ct2_b   = (const float*)d_in[6];
    const float* codebook= (const float*)d_in[7];
    const float* c1_w    = (const float*)d_in[8];
    const float* c1_b    = (const float*)d_in[9];
    const float* c2_w    = (const float*)d_in[10];
    const float* c2_b    = (const float*)d_in[11];
    const float* a1_w    = (const float*)d_in[12];
    const float* a1_b    = (const float*)d_in[13];
    const float* a2_w    = (const float*)d_in[14];
    const float* a2_b    = (const float*)d_in[15];
    float* out = (float*)d_out;

    float* ws     = (float*)d_ws;
    float* feat   = ws;                      // 8388608
    float* s9     = feat + 8388608;          // 2359296
    float* tapabc = s9 + 2359296;            // 4800
    float* P      = tapabc + 4800;           // 65536
    float* M      = P + 65536;               // 409600
    float* partial= M + 409600;              // 1024
    float* w1t    = partial + 1024;          // 204800
    float* Wsum   = w1t + 204800;            // 204800
    short* wtall  = (short*)(Wsum + 204800); // 124928 shorts
    short* wtA    = wtall;
    short* wtC1   = wtall + 18432;
    short* wtC2   = wtall + 36864;
    short* wtT2   = wtall + 73728;
    unsigned short* tmpb    = (unsigned short*)(wtall + 124928);  // 16777216
    unsigned short* qfeatb  = tmpb + 16777216;                    // 8388608
    unsigned short* colorsb = qfeatb + 8388608;                   // 16777216

    w1t_kernel<<<800, 256, 0, stream>>>(ct1_w, w1t);
    tapabc_kernel<<<25, 192, 0, stream>>>(pos_w, pos_b, w1t, tapabc);
    pfill_kernel<<<64, 1024, 0, stream>>>(tapabc, ct1_b, P);
    wsum_kernel<<<800, 256, 0, stream>>>(ct1_w, Wsum);
    m_kernel<<<dim3(256, 25), 64, 0, stream>>>(latent, Wsum, M);
    prep_all_kernel<<<488, 256, 0, stream>>>(a1_w, c1_w, c2_w, ct2_w, wtall);

    conv5_kernel<<<dim3(256, 4), 256, 0, stream>>>(M, P, wtT2, ct2_b, feat);
    // alpha head: a1 conv with fused a2 channel-dot -> s9 -> softmax
    conv3_kernel<32, 64, 1, 0, 0, 1><<<dim3(256, 4), 256, 0, stream>>>(
        feat, wtA, a1_b, nullptr, a2_w, s9);
    a2soft_kernel<<<128, 256, 0, stream>>>(s9, a2_b, out);
    // VQ
    vq_kernel<<<1024, 256, 0, stream>>>(feat, codebook, qfeatb, partial);
    // color head
    conv3_kernel<32, 64, 1, 1, 1, 0><<<dim3(256, 4), 256, 0, stream>>>(
        qfeatb, wtC1, c1_b, tmpb, nullptr, nullptr);
    conv3_kernel<64, 64, 0, 1, 1, 0><<<dim3(256, 4), 256, 0, stream>>>(
        tmpb, wtC2, c2_b, colorsb, nullptr, nullptr);
    recon_kernel<<<8192, 256, 0, stream>>>(colorsb, out);
    loss_kernel<<<1, 256, 0, stream>>>(partial, out);
}

// Round 7
// 302.576 us; speedup vs baseline: 1.3679x; 1.1166x over previous
//
#include <hip/hip_runtime.h>
#include <math.h>

#define AOFF 2097152   // recon = 32*64*1024 floats, alphas follow
#define LOFF 2359296   // AOFF + 32*8*1024

typedef __attribute__((ext_vector_type(8))) short short8;
typedef __attribute__((ext_vector_type(4))) float f32x4;

__device__ __forceinline__ int clsf(int v) { return v < 2 ? v : (v > 29 ? v - 27 : 2); }

__device__ __forceinline__ unsigned int f2bfu(float x) {
    unsigned int u = __float_as_uint(x);
    return (u + 0x7FFFu + ((u >> 16) & 1u)) >> 16;
}
__device__ __forceinline__ unsigned int cvt2(float a, float b) {
    return f2bfu(a) | (f2bfu(b) << 16);
}
__device__ __forceinline__ float bf2f(unsigned short u) {
    return __uint_as_float(((unsigned int)u) << 16);
}

// ---------------- w1 transpose: w1t[tap][i][o] ----------------
__global__ void w1t_kernel(const float* __restrict__ w1, float* __restrict__ w1t) {
    int idx = blockIdx.x * 256 + threadIdx.x;
    if (idx >= 204800) return;
    int tap = idx % 25, rest = idx / 25;       // rest = i*64+o
    w1t[tap * 8192 + rest] = w1[idx];
}

// ---------------- tapabc: per-tap dot with affine pos coeffs ----------------
__global__ void tapabc_kernel(const float* __restrict__ pw, const float* __restrict__ pb,
                              const float* __restrict__ w1t, float* __restrict__ tapabc) {
    __shared__ float A3[384];
    int tap = blockIdx.x, t = threadIdx.x;     // 192 threads
    if (t < 128) {
        float p0 = pw[t * 4], p1 = pw[t * 4 + 1], p2 = pw[t * 4 + 2], p3 = pw[t * 4 + 3];
        A3[t] = p2 + p3 + pb[t];
        A3[128 + t] = p0 - p2;
        A3[256 + t] = p1 - p3;
    }
    __syncthreads();
    int o = t & 63, comp = t >> 6;
    const float* wp = w1t + tap * 8192 + o;
    const float* a = A3 + comp * 128;
    float s = 0.f;
    for (int i = 0; i < 128; ++i) s = fmaf(wp[i * 64], a[i], s);
    tapabc[(tap * 64 + o) * 3 + comp] = s;
}

// ---------------- P fill: writes channel-PAIR interleaved layout ----------------
// P2 as float2[ip][yx] covering channels (2ip, 2ip+1)
__global__ void pfill_kernel(const float* __restrict__ tapabc, const float* __restrict__ b1,
                             float* __restrict__ P2) {
    __shared__ float uv[75];
    int o = blockIdx.x, t = threadIdx.x;       // 1024 threads
    if (t < 75) {
        int cls = t / 3, comp = t % 3;
        int cy = cls / 5, cx = cls % 5;
        const int klo[5] = {2, 1, 0, 0, 0}, khi[5] = {4, 4, 4, 3, 2};
        const float inv31 = 1.f / 31.f;
        float s = (comp == 0) ? b1[o] : 0.f;
        for (int ky = klo[cy]; ky <= khi[cy]; ++ky)
            for (int kx = klo[cx]; kx <= khi[cx]; ++kx) {
                int tap = (4 - ky) * 5 + (4 - kx);
                const float* tp = &tapabc[(tap * 64 + o) * 3];
                if (comp == 0) s += tp[0] + tp[1] * (ky - 2) * inv31 + tp[2] * (kx - 2) * inv31;
                else if (comp == 1) s += tp[1] * inv31;
                else s += tp[2] * inv31;
            }
        uv[t] = s;
    }
    __syncthreads();
    int y = t >> 5, x = t & 31;
    int cls = clsf(y) * 5 + clsf(x);
    float val = uv[cls * 3] + uv[cls * 3 + 1] * y + uv[cls * 3 + 2] * x;
    P2[((o >> 1) << 11) + (t << 1) + (o & 1)] = val;
}

// ---------------- Wsum[cls][i][o] ----------------
__global__ void wsum_kernel(const float* __restrict__ w1, float* __restrict__ Wsum) {
    int idx = blockIdx.x * 256 + threadIdx.x;
    if (idx >= 25 * 128 * 64) return;
    int cls = idx >> 13;
    int i = (idx >> 6) & 127;
    int o = idx & 63;
    int cy = cls / 5, cx = cls % 5;
    const int klo[5] = {2, 1, 0, 0, 0}, khi[5] = {4, 4, 4, 3, 2};
    float s = 0.f;
    for (int ky = klo[cy]; ky <= khi[cy]; ++ky)
        for (int kx = klo[cx]; kx <= khi[cx]; ++kx)
            s += w1[(i * 64 + o) * 25 + (4 - ky) * 5 + (4 - kx)];
    Wsum[idx] = s;
}

// ---------------- M[n][cls][o] = latent[n,:] . Wsum[cls,:,o] ----------------
__global__ void m_kernel(const float* __restrict__ latent, const float* __restrict__ Wsum,
                         float* __restrict__ M) {
    int n = blockIdx.x, cls = blockIdx.y, o = threadIdx.x;
    const float* l = &latent[n * 128];
    const float* w = &Wsum[cls * 8192 + o];
    float a0 = 0.f, a1 = 0.f;
    for (int i = 0; i < 128; i += 2) {
        a0 = fmaf(l[i], w[i * 64], a0);
        a1 = fmaf(l[i + 1], w[(i + 1) * 64], a1);
    }
    M[(n * 25 + cls) * 64 + o] = a0 + a1;
}

// ---------------- merged weight prep (4 segments) ----------------
__global__ void prep_all_kernel(const float* __restrict__ a1w, const float* __restrict__ c1w,
                                const float* __restrict__ c2w, const float* __restrict__ ct2w,
                                short* __restrict__ wtall) {
    int gid = blockIdx.x * 256 + threadIdx.x;
    if (gid < 36864) {                                  // a1 / c1 : I=32,O=64
        const float* src = gid < 18432 ? a1w : c1w;
        int idx = gid < 18432 ? gid : gid - 18432;
        int j = idx & 7, fi = idx >> 3;
        int o = fi % 64, g = (fi / 64) & 3, t = fi / 256;
        int i = g * 8 + j;
        wtall[gid] = (short)f2bfu(src[(o * 32 + i) * 9 + (t / 3) * 3 + (t % 3)]);
    } else if (gid < 73728) {                           // c2 : I=64,O=64
        int idx = gid - 36864;
        int j = idx & 7, fi = idx >> 3;
        int o = fi % 64, g = (fi / 64) & 3, ks = (fi / 256) & 1, t = fi / 512;
        int i = ks * 32 + g * 8 + j;
        wtall[gid] = (short)f2bfu(c2w[(o * 64 + i) * 9 + (t / 3) * 3 + (t % 3)]);
    } else if (gid < 124928) {                          // convT2 : flipped 5x5
        int idx = gid - 73728;
        int j = idx & 7, fi = idx >> 3;
        int o = fi & 31, g = (fi >> 5) & 3, ks = (fi >> 7) & 1, t = fi >> 8;
        int i = ks * 32 + g * 8 + j;
        int ky = t / 5, kx = t % 5;
        wtall[gid] = (short)f2bfu(ct2w[((i * 32 + o) * 5 + (4 - ky)) * 5 + (4 - kx)]);
    }
}

// ---------------- conv5 (convT2) v2: split-K staging, 4 blocks/CU ----------------
// tile holds HALF the channels [12 rows][36 cols][32 ch] bf16 = 27.6 KB;
// two stage+compute phases (ks = 0,1). Swizzle key (cx&3)<<4 stays inside
// the 64B channel block (I=32), applied identically on write and read.
__global__ __launch_bounds__(256, 4) void conv5_kernel(
        const float* __restrict__ M, const float* __restrict__ P2,
        const short* __restrict__ wt, const float* __restrict__ b2,
        float* __restrict__ feat) {
    __shared__ __align__(16) short tile[12 * 36 * 32];  // 27648 B
    __shared__ float Ml[1600];                          // 6400 B
    const int n = blockIdx.x, y0 = blockIdx.y * 8;
    const int tid = threadIdx.x, w = tid >> 6, l = tid & 63;
    const int lx = l & 15, lg = l >> 4;

    for (int e = tid; e < 1600; e += 256) Ml[e] = M[n * 1600 + e];
    __syncthreads();

    f32x4 acc[2][2][2];
    #pragma unroll
    for (int m = 0; m < 2; ++m)
        #pragma unroll
        for (int q = 0; q < 2; ++q)
            #pragma unroll
            for (int c = 0; c < 2; ++c) acc[m][q][c] = (f32x4){0.f, 0.f, 0.f, 0.f};

    #pragma unroll 1
    for (int ks = 0; ks < 2; ++ks) {
        if (ks) __syncthreads();              // compute(0) readers done before restage
        for (int e = tid; e < 6912; e += 256) {
            int cx = e % 36;
            int q = e / 36;
            int ipl = q & 15;                 // channel pair within half
            int r = q >> 4;
            int gy = y0 - 2 + r, gx = cx - 2;
            unsigned int pack = 0u;
            if (gy >= 0 && gy < 32 && gx >= 0 && gx < 32) {
                int cls = clsf(gy) * 5 + clsf(gx);
                int pp = gy * 32 + gx;
                float2 pv = ((const float2*)P2)[((ks * 16 + ipl) << 10) + pp];
                float2 ml = ((const float2*)Ml)[cls * 32 + ks * 16 + ipl];
                pack = cvt2(fmaxf(ml.x + pv.x, 0.f), fmaxf(ml.y + pv.y, 0.f));
            }
            int off = ((r * 36 + cx) * 32 + 2 * ipl) * 2;
            off ^= (cx & 3) << 4;
            *(unsigned int*)((char*)tile + off) = pack;
        }
        __syncthreads();
        #pragma unroll 1
        for (int kx = 0; kx < 5; ++kx) {
            short8 af[5][2];
            #pragma unroll
            for (int ky = 0; ky < 5; ++ky)
                #pragma unroll
                for (int m = 0; m < 2; ++m)
                    af[ky][m] = *(const short8*)(wt + (ky * 5 + kx) * 2048 +
                                                 ((ks * 4 + lg) * 32 + m * 16 + lx) * 8);
            const int key = ((kx + lx) & 3) << 4;
            #pragma unroll
            for (int colf = 0; colf < 2; ++colf) {
                const int cbase = ((2 * w) * 36 + kx + colf * 16 + lx) * 64 + lg * 16;
                short8 bc[6];
                #pragma unroll
                for (int ir = 0; ir < 6; ++ir)
                    bc[ir] = *(const short8*)((char*)tile + ((cbase + ir * (36 * 64)) ^ key));
                #pragma unroll
                for (int ky = 0; ky < 5; ++ky)
                    #pragma unroll
                    for (int q = 0; q < 2; ++q)
                        #pragma unroll
                        for (int m = 0; m < 2; ++m)
                            acc[m][q][colf] = __builtin_amdgcn_mfma_f32_16x16x32_bf16(
                                af[ky][m], bc[q + ky], acc[m][q][colf], 0, 0, 0);
            }
        }
    }

    #pragma unroll
    for (int m = 0; m < 2; ++m)
        #pragma unroll
        for (int q = 0; q < 2; ++q)
            #pragma unroll
            for (int colf = 0; colf < 2; ++colf) {
                int yl = 2 * w + q, x = colf * 16 + lx;
                #pragma unroll
                for (int r = 0; r < 4; ++r) {
                    int och = m * 16 + lg * 4 + r;
                    float v = fmaxf(acc[m][q][colf][r] + b2[och], 0.f);
                    feat[(n * 32 + och) * 1024 + (y0 + yl) * 32 + x] = v;
                }
            }
}

// ---------------- conv3: A from global, B row-cached; optional fused a2-dot ----------------
template<int I, int O, int ACT, int INBF, int OUTBF, int FUSEA2>
__global__ __launch_bounds__(256) void conv3_kernel(
        const void* __restrict__ in_, const short* __restrict__ wt,
        const float* __restrict__ bias, void* __restrict__ out_,
        const float* __restrict__ a2w, float* __restrict__ s9) {
    constexpr int XC = 34, ROWS = 10, KS = I / 32, MF = O / 16, IH = I / 2;
    constexpr int TILE = ROWS * XC * I;
    constexpr int SMSZ = (FUSEA2 && TILE < 16384) ? 16384 : TILE;
    constexpr int ABUF = KS * 4 * O * 8;
    __shared__ __align__(16) short smem[SMSZ];
    __shared__ float wl[FUSEA2 ? 576 : 1];
    const int n = blockIdx.x, y0 = blockIdx.y * 8;
    const int tid = threadIdx.x, w = tid >> 6, l = tid & 63;
    const int lx = l & 15, lg = l >> 4;

    if constexpr (FUSEA2)
        for (int e = tid; e < 576; e += 256) wl[e] = a2w[e];

    for (int e = tid; e < ROWS * XC * IH; e += 256) {
        int cx = e % XC;
        int q = e / XC;
        int ip = q % IH;
        int r = q / IH;
        int gy = y0 - 1 + r, gx = cx - 1;
        unsigned int pack = 0u;
        if (gy >= 0 && gy < 32 && gx >= 0 && gx < 32) {
            if constexpr (INBF) {
                const unsigned short* p =
                    (const unsigned short*)in_ + (n * I + 2 * ip) * 1024 + gy * 32 + gx;
                pack = (unsigned int)p[0] | ((unsigned int)p[1024] << 16);
            } else {
                const float* p = (const float*)in_ + (n * I + 2 * ip) * 1024 + gy * 32 + gx;
                pack = cvt2(p[0], p[1024]);
            }
        }
        int off = ((r * XC + cx) * I + 2 * ip) * 2;
        off ^= (cx & 7) << 4;
        *(unsigned int*)((char*)smem + off) = pack;
    }
    __syncthreads();

    f32x4 acc[MF][2][2];
    #pragma unroll
    for (int m = 0; m < MF; ++m)
        #pragma unroll
        for (int q = 0; q < 2; ++q)
            #pragma unroll
            for (int c = 0; c < 2; ++c) acc[m][q][c] = (f32x4){0.f, 0.f, 0.f, 0.f};

    #pragma unroll 1
    for (int ks = 0; ks < KS; ++ks) {
        #pragma unroll 1
        for (int kx = 0; kx < 3; ++kx) {
            short8 af[3][MF];
            #pragma unroll
            for (int ky = 0; ky < 3; ++ky)
                #pragma unroll
                for (int m = 0; m < MF; ++m)
                    af[ky][m] = *(const short8*)(wt + (ky * 3 + kx) * ABUF +
                                                 ((ks * 4 + lg) * O + m * 16 + lx) * 8);
            const int key = ((kx + lx) & 7) << 4;
            #pragma unroll
            for (int colf = 0; colf < 2; ++colf) {
                const int cbase = ((2 * w) * XC + kx + colf * 16 + lx) * (I * 2)
                                + (ks * 32 + lg * 8) * 2;
                short8 bc[4];
                #pragma unroll
                for (int ir = 0; ir < 4; ++ir)
                    bc[ir] = *(const short8*)((char*)smem + ((cbase + ir * (XC * I * 2)) ^ key));
                #pragma unroll
                for (int ky = 0; ky < 3; ++ky)
                    #pragma unroll
                    for (int q = 0; q < 2; ++q)
                        #pragma unroll
                        for (int m = 0; m < MF; ++m)
                            acc[m][q][colf] = __builtin_amdgcn_mfma_f32_16x16x32_bf16(
                                af[ky][m], bc[q + ky], acc[m][q][colf], 0, 0, 0);
            }
        }
    }

    if constexpr (!FUSEA2) {
        #pragma unroll
        for (int m = 0; m < MF; ++m)
            #pragma unroll
            for (int q = 0; q < 2; ++q)
                #pragma unroll
                for (int colf = 0; colf < 2; ++colf) {
                    int yl = 2 * w + q, x = colf * 16 + lx;
                    #pragma unroll
                    for (int r = 0; r < 4; ++r) {
                        int och = m * 16 + lg * 4 + r;
                        float v = acc[m][q][colf][r] + bias[och];
                        if (ACT == 1) v = v / (1.f + expf(-v));
                        int oidx = (n * O + och) * 1024 + (y0 + yl) * 32 + x;
                        if constexpr (OUTBF)
                            ((unsigned short*)out_)[oidx] = (unsigned short)f2bfu(v);
                        else
                            ((float*)out_)[oidx] = v;
                    }
                }
    } else {
        __syncthreads();
        #pragma unroll
        for (int m = 0; m < MF; ++m)
            #pragma unroll
            for (int q = 0; q < 2; ++q)
                #pragma unroll
                for (int colf = 0; colf < 2; ++colf) {
                    int px_lin = (2 * w + q) * 32 + colf * 16 + lx;
                    unsigned long long pk = 0ull;
                    #pragma unroll
                    for (int r = 0; r < 4; ++r) {
                        int och = m * 16 + lg * 4 + r;
                        float v = acc[m][q][colf][r] + bias[och];
                        v = v / (1.f + expf(-v));
                        pk |= (unsigned long long)f2bfu(v) << (16 * r);
                    }
                    int off = (px_lin * 64 + m * 16 + lg * 4) * 2;
                    off ^= (px_lin & 7) << 4;
                    *(unsigned long long*)((char*)smem + off) = pk;
                }
        __syncthreads();
        float a1v[64];
        {
            const int key2 = (tid & 7) << 4;
            #pragma unroll
            for (int c = 0; c < 8; ++c) {
                short8 v = *(const short8*)((char*)smem + (((tid * 64 + c * 8) * 2) ^ key2));
                #pragma unroll
                for (int j = 0; j < 8; ++j) a1v[c * 8 + j] = bf2f((unsigned short)v[j]);
            }
        }
        int rr = tid >> 5, x = tid & 31;
        #pragma unroll 1
        for (int tap = 0; tap < 9; ++tap) {
            float s = 0.f;
            #pragma unroll
            for (int ch = 0; ch < 64; ++ch) s = fmaf(a1v[ch], wl[ch * 9 + tap], s);
            s9[(tap << 18) + (n << 10) + (y0 + rr) * 32 + x] = s;
        }
    }
}

// ---------------- a2 tap-sum + slot softmax ----------------
__global__ void a2soft_kernel(const float* __restrict__ s9, const float* __restrict__ b2,
                              float* __restrict__ outp) {
    int idx = blockIdx.x * 256 + threadIdx.x;
    if (idx >= 32 * 1024) return;
    int bb = idx >> 10, yx = idx & 1023;
    int y = yx >> 5, x = yx & 31;
    float v[8];
    float bias = b2[0];
    #pragma unroll
    for (int s = 0; s < 8; ++s) {
        int n = bb * 8 + s;
        float a = bias;
        #pragma unroll
        for (int ky = 0; ky < 3; ++ky) {
            int yy = y + ky - 1;
            if (yy < 0 || yy > 31) continue;
            #pragma unroll
            for (int kx = 0; kx < 3; ++kx) {
                int xx = x + kx - 1;
                if (xx < 0 || xx > 31) continue;
                a += s9[((ky * 3 + kx) << 18) + (n << 10) + yy * 32 + xx];
            }
        }
        v[s] = a;
    }
    float m = -3.4e38f;
    #pragma unroll
    for (int s = 0; s < 8; ++s) m = fmaxf(m, v[s]);
    float sum = 0.f;
    #pragma unroll
    for (int s = 0; s < 8; ++s) { v[s] = expf(v[s] - m); sum += v[s]; }
    float inv = 1.f / sum;
    #pragma unroll
    for (int s = 0; s < 8; ++s) outp[AOFF + ((bb * 8 + s) << 10) + yx] = v[s] * inv;
}

// ---------------- VQ ----------------
__global__ void vq_kernel(const float* __restrict__ feat, const float* __restrict__ codebook,
                          unsigned short* __restrict__ qfeat, float* __restrict__ partial) {
    __shared__ float cb[4096];
    __shared__ float cn[128];
    __shared__ float wsumr[4];
    int t = threadIdx.x;
    for (int e = t; e < 4096; e += 256) cb[e] = codebook[e];
    __syncthreads();
    if (t < 128) {
        float s = 0.f;
        #pragma unroll
        for (int c = 0; c < 32; ++c) { float v = cb[t * 32 + c]; s = fmaf(v, v, s); }
        cn[t] = s;
    }
    __syncthreads();
    int idx = blockIdx.x * 256 + t;
    int n = idx >> 10, yx = idx & 1023;
    float f[32];
    #pragma unroll
    for (int c = 0; c < 32; ++c) f[c] = feat[(n * 32 + c) * 1024 + yx];
    float best = 3.4e38f; int bi = 0;
    for (int k = 0; k < 128; ++k) {
        const float* cp = &cb[k * 32];
        float d0 = 0.f, d1 = 0.f, d2 = 0.f, d3 = 0.f;
        #pragma unroll
        for (int c = 0; c < 32; c += 4) {
            d0 = fmaf(f[c], cp[c], d0);
            d1 = fmaf(f[c + 1], cp[c + 1], d1);
            d2 = fmaf(f[c + 2], cp[c + 2], d2);
            d3 = fmaf(f[c + 3], cp[c + 3], d3);
        }
        float d = cn[k] - 2.f * ((d0 + d1) + (d2 + d3));
        if (d < best) { best = d; bi = k; }
    }
    float lsum = 0.f;
    const float* q = &cb[bi * 32];
    #pragma unroll
    for (int c = 0; c < 32; ++c) {
        float qv = q[c];
        qfeat[(n * 32 + c) * 1024 + yx] = (unsigned short)f2bfu(qv);
        float dd = qv - f[c];
        lsum = fmaf(dd, dd, lsum);
    }
    for (int off = 32; off > 0; off >>= 1) lsum += __shfl_down(lsum, off);
    int lane = t & 63, wid = t >> 6;
    if (lane == 0) wsumr[wid] = lsum;
    __syncthreads();
    if (t == 0) partial[blockIdx.x] = (wsumr[0] + wsumr[1]) + (wsumr[2] + wsumr[3]);
}

__global__ void recon_kernel(const unsigned short* __restrict__ colors, float* __restrict__ outp) {
    int idx = blockIdx.x * 256 + threadIdx.x;
    int yx = idx & 1023;
    int v = (idx >> 10) & 63;
    int bb = idx >> 16;
    float acc = 0.f;
    #pragma unroll
    for (int s = 0; s < 8; ++s) {
        float a = outp[AOFF + ((bb * 8 + s) << 10) + yx];
        float c = bf2f(colors[((bb * 8 + s) * 64 + v) * 1024 + yx]);
        acc = fmaf(a, c, acc);
    }
    outp[idx] = acc;
}

__global__ void loss_kernel(const float* __restrict__ partial, float* __restrict__ outp) {
    __shared__ float red[4];
    int t = threadIdx.x;
    float s = 0.f;
    for (int i = t; i < 1024; i += 256) s += partial[i];
    for (int o = 32; o > 0; o >>= 1) s += __shfl_down(s, o);
    if ((t & 63) == 0) red[t >> 6] = s;
    __syncthreads();
    if (t == 0) outp[LOFF] = 1.25f * ((red[0] + red[1]) + (red[2] + red[3])) / 8388608.0f;
}

extern "C" void kernel_launch(void* const* d_in, const int* in_sizes, int n_in,
                              void* d_out, int out_size, void* d_ws, size_t ws_size,
                              hipStream_t stream) {
    const float* latent  = (const float*)d_in[0];
    const float* pos_w   = (const float*)d_in[1];
    const float* pos_b   = (const float*)d_in[2];
    const float* ct1_w   = (const float*)d_in[3];
    const float* ct1_b   = (const float*)d_in[4];
    const float* ct2_w   = (const float*)d_in[5];
    const float* ct2_b   = (const float*)d_in[6];
    const float* codebook= (const float*)d_in[7];
    const float* c1_w    = (const float*)d_in[8];
    const float* c1_b    = (const float*)d_in[9];
    const float* c2_w    = (const float*)d_in[10];
    const float* c2_b    = (const float*)d_in[11];
    const float* a1_w    = (const float*)d_in[12];
    const float* a1_b    = (const float*)d_in[13];
    const float* a2_w    = (const float*)d_in[14];
    const float* a2_b    = (const float*)d_in[15];
    float* out = (float*)d_out;

    float* ws     = (float*)d_ws;
    float* feat   = ws;                      // 8388608
    float* s9     = feat + 8388608;          // 2359296
    float* tapabc = s9 + 2359296;            // 4800
    float* P      = tapabc + 4800;           // 65536 (pair-interleaved float2 layout)
    float* M      = P + 65536;               // 409600
    float* partial= M + 409600;              // 1024
    float* w1t    = partial + 1024;          // 204800
    float* Wsum   = w1t + 204800;            // 204800
    short* wtall  = (short*)(Wsum + 204800); // 124928 shorts
    short* wtA    = wtall;
    short* wtC1   = wtall + 18432;
    short* wtC2   = wtall + 36864;
    short* wtT2   = wtall + 73728;
    unsigned short* tmpb    = (unsigned short*)(wtall + 124928);  // 16777216
    unsigned short* qfeatb  = tmpb + 16777216;                    // 8388608
    unsigned short* colorsb = qfeatb + 8388608;                   // 16777216

    w1t_kernel<<<800, 256, 0, stream>>>(ct1_w, w1t);
    tapabc_kernel<<<25, 192, 0, stream>>>(pos_w, pos_b, w1t, tapabc);
    pfill_kernel<<<64, 1024, 0, stream>>>(tapabc, ct1_b, P);
    wsum_kernel<<<800, 256, 0, stream>>>(ct1_w, Wsum);
    m_kernel<<<dim3(256, 25), 64, 0, stream>>>(latent, Wsum, M);
    prep_all_kernel<<<488, 256, 0, stream>>>(a1_w, c1_w, c2_w, ct2_w, wtall);

    conv5_kernel<<<dim3(256, 4), 256, 0, stream>>>(M, P, wtT2, ct2_b, feat);
    // alpha head: a1 conv with fused a2 channel-dot -> s9 -> softmax
    conv3_kernel<32, 64, 1, 0, 0, 1><<<dim3(256, 4), 256, 0, stream>>>(
        feat, wtA, a1_b, nullptr, a2_w, s9);
    a2soft_kernel<<<128, 256, 0, stream>>>(s9, a2_b, out);
    // VQ
    vq_kernel<<<1024, 256, 0, stream>>>(feat, codebook, qfeatb, partial);
    // color head
    conv3_kernel<32, 64, 1, 1, 1, 0><<<dim3(256, 4), 256, 0, stream>>>(
        qfeatb, wtC1, c1_b, tmpb, nullptr, nullptr);
    conv3_kernel<64, 64, 0, 1, 1, 0><<<dim3(256, 4), 256, 0, stream>>>(
        tmpb, wtC2, c2_b, colorsb, nullptr, nullptr);
    recon_kernel<<<8192, 256, 0, stream>>>(colorsb, out);
    loss_kernel<<<1, 256, 0, stream>>>(partial, out);
}

// Round 8
// 261.610 us; speedup vs baseline: 1.5820x; 1.1566x over previous
//
#include <hip/hip_runtime.h>
#include <math.h>

#define AOFF 2097152   // recon = 32*64*1024 floats, alphas follow
#define LOFF 2359296   // AOFF + 32*8*1024

typedef __attribute__((ext_vector_type(8))) short short8;
typedef __attribute__((ext_vector_type(4))) float f32x4;

__device__ __forceinline__ int clsf(int v) { return v < 2 ? v : (v > 29 ? v - 27 : 2); }

__device__ __forceinline__ unsigned int f2bfu(float x) {
    unsigned int u = __float_as_uint(x);
    return (u + 0x7FFFu + ((u >> 16) & 1u)) >> 16;
}
__device__ __forceinline__ unsigned int cvt2(float a, float b) {
    return f2bfu(a) | (f2bfu(b) << 16);
}
__device__ __forceinline__ float bf2f(unsigned short u) {
    return __uint_as_float(((unsigned int)u) << 16);
}

// ---------------- w1 transpose: w1t[tap][i][o] ----------------
__global__ void w1t_kernel(const float* __restrict__ w1, float* __restrict__ w1t) {
    int idx = blockIdx.x * 256 + threadIdx.x;
    if (idx >= 204800) return;
    int tap = idx % 25, rest = idx / 25;       // rest = i*64+o
    w1t[tap * 8192 + rest] = w1[idx];
}

// ---------------- tapabc: per-tap dot with affine pos coeffs ----------------
__global__ void tapabc_kernel(const float* __restrict__ pw, const float* __restrict__ pb,
                              const float* __restrict__ w1t, float* __restrict__ tapabc) {
    __shared__ float A3[384];
    int tap = blockIdx.x, t = threadIdx.x;     // 192 threads
    if (t < 128) {
        float p0 = pw[t * 4], p1 = pw[t * 4 + 1], p2 = pw[t * 4 + 2], p3 = pw[t * 4 + 3];
        A3[t] = p2 + p3 + pb[t];
        A3[128 + t] = p0 - p2;
        A3[256 + t] = p1 - p3;
    }
    __syncthreads();
    int o = t & 63, comp = t >> 6;
    const float* wp = w1t + tap * 8192 + o;
    const float* a = A3 + comp * 128;
    float s = 0.f;
    for (int i = 0; i < 128; ++i) s = fmaf(wp[i * 64], a[i], s);
    tapabc[(tap * 64 + o) * 3 + comp] = s;
}

// ---------------- P fill: writes channel-PAIR interleaved layout ----------------
__global__ void pfill_kernel(const float* __restrict__ tapabc, const float* __restrict__ b1,
                             float* __restrict__ P2) {
    __shared__ float uv[75];
    int o = blockIdx.x, t = threadIdx.x;       // 1024 threads
    if (t < 75) {
        int cls = t / 3, comp = t % 3;
        int cy = cls / 5, cx = cls % 5;
        const int klo[5] = {2, 1, 0, 0, 0}, khi[5] = {4, 4, 4, 3, 2};
        const float inv31 = 1.f / 31.f;
        float s = (comp == 0) ? b1[o] : 0.f;
        for (int ky = klo[cy]; ky <= khi[cy]; ++ky)
            for (int kx = klo[cx]; kx <= khi[cx]; ++kx) {
                int tap = (4 - ky) * 5 + (4 - kx);
                const float* tp = &tapabc[(tap * 64 + o) * 3];
                if (comp == 0) s += tp[0] + tp[1] * (ky - 2) * inv31 + tp[2] * (kx - 2) * inv31;
                else if (comp == 1) s += tp[1] * inv31;
                else s += tp[2] * inv31;
            }
        uv[t] = s;
    }
    __syncthreads();
    int y = t >> 5, x = t & 31;
    int cls = clsf(y) * 5 + clsf(x);
    float val = uv[cls * 3] + uv[cls * 3 + 1] * y + uv[cls * 3 + 2] * x;
    P2[((o >> 1) << 11) + (t << 1) + (o & 1)] = val;
}

// ---------------- Wsum[cls][i][o] ----------------
__global__ void wsum_kernel(const float* __restrict__ w1, float* __restrict__ Wsum) {
    int idx = blockIdx.x * 256 + threadIdx.x;
    if (idx >= 25 * 128 * 64) return;
    int cls = idx >> 13;
    int i = (idx >> 6) & 127;
    int o = idx & 63;
    int cy = cls / 5, cx = cls % 5;
    const int klo[5] = {2, 1, 0, 0, 0}, khi[5] = {4, 4, 4, 3, 2};
    float s = 0.f;
    for (int ky = klo[cy]; ky <= khi[cy]; ++ky)
        for (int kx = klo[cx]; kx <= khi[cx]; ++kx)
            s += w1[(i * 64 + o) * 25 + (4 - ky) * 5 + (4 - kx)];
    Wsum[idx] = s;
}

// ---------------- M[n][cls][o] = latent[n,:] . Wsum[cls,:,o] ----------------
__global__ void m_kernel(const float* __restrict__ latent, const float* __restrict__ Wsum,
                         float* __restrict__ M) {
    int n = blockIdx.x, cls = blockIdx.y, o = threadIdx.x;
    const float* l = &latent[n * 128];
    const float* w = &Wsum[cls * 8192 + o];
    float a0 = 0.f, a1 = 0.f;
    for (int i = 0; i < 128; i += 2) {
        a0 = fmaf(l[i], w[i * 64], a0);
        a1 = fmaf(l[i + 1], w[(i + 1) * 64], a1);
    }
    M[(n * 25 + cls) * 64 + o] = a0 + a1;
}

// ---------------- merged weight prep (4 segments) ----------------
__global__ void prep_all_kernel(const float* __restrict__ a1w, const float* __restrict__ c1w,
                                const float* __restrict__ c2w, const float* __restrict__ ct2w,
                                short* __restrict__ wtall) {
    int gid = blockIdx.x * 256 + threadIdx.x;
    if (gid < 36864) {                                  // a1 / c1 : I=32,O=64
        const float* src = gid < 18432 ? a1w : c1w;
        int idx = gid < 18432 ? gid : gid - 18432;
        int j = idx & 7, fi = idx >> 3;
        int o = fi % 64, g = (fi / 64) & 3, t = fi / 256;
        int i = g * 8 + j;
        wtall[gid] = (short)f2bfu(src[(o * 32 + i) * 9 + (t / 3) * 3 + (t % 3)]);
    } else if (gid < 73728) {                           // c2 : I=64,O=64
        int idx = gid - 36864;
        int j = idx & 7, fi = idx >> 3;
        int o = fi % 64, g = (fi / 64) & 3, ks = (fi / 256) & 1, t = fi / 512;
        int i = ks * 32 + g * 8 + j;
        wtall[gid] = (short)f2bfu(c2w[(o * 64 + i) * 9 + (t / 3) * 3 + (t % 3)]);
    } else if (gid < 124928) {                          // convT2 : flipped 5x5
        int idx = gid - 73728;
        int j = idx & 7, fi = idx >> 3;
        int o = fi & 31, g = (fi >> 5) & 3, ks = (fi >> 7) & 1, t = fi >> 8;
        int i = ks * 32 + g * 8 + j;
        int ky = t / 5, kx = t % 5;
        wtall[gid] = (short)f2bfu(ct2w[((i * 32 + o) * 5 + (4 - ky)) * 5 + (4 - kx)]);
    }
}

// ---------------- conv5 (convT2): split-K staging, 4 blocks/CU ----------------
__global__ __launch_bounds__(256, 4) void conv5_kernel(
        const float* __restrict__ M, const float* __restrict__ P2,
        const short* __restrict__ wt, const float* __restrict__ b2,
        float* __restrict__ feat) {
    __shared__ __align__(16) short tile[12 * 36 * 32];  // 27648 B
    __shared__ float Ml[1600];                          // 6400 B
    const int n = blockIdx.x, y0 = blockIdx.y * 8;
    const int tid = threadIdx.x, w = tid >> 6, l = tid & 63;
    const int lx = l & 15, lg = l >> 4;

    for (int e = tid; e < 1600; e += 256) Ml[e] = M[n * 1600 + e];
    __syncthreads();

    f32x4 acc[2][2][2];
    #pragma unroll
    for (int m = 0; m < 2; ++m)
        #pragma unroll
        for (int q = 0; q < 2; ++q)
            #pragma unroll
            for (int c = 0; c < 2; ++c) acc[m][q][c] = (f32x4){0.f, 0.f, 0.f, 0.f};

    #pragma unroll 1
    for (int ks = 0; ks < 2; ++ks) {
        if (ks) __syncthreads();
        for (int e = tid; e < 6912; e += 256) {
            int cx = e % 36;
            int q = e / 36;
            int ipl = q & 15;
            int r = q >> 4;
            int gy = y0 - 2 + r, gx = cx - 2;
            unsigned int pack = 0u;
            if (gy >= 0 && gy < 32 && gx >= 0 && gx < 32) {
                int cls = clsf(gy) * 5 + clsf(gx);
                int pp = gy * 32 + gx;
                float2 pv = ((const float2*)P2)[((ks * 16 + ipl) << 10) + pp];
                float2 ml = ((const float2*)Ml)[cls * 32 + ks * 16 + ipl];
                pack = cvt2(fmaxf(ml.x + pv.x, 0.f), fmaxf(ml.y + pv.y, 0.f));
            }
            int off = ((r * 36 + cx) * 32 + 2 * ipl) * 2;
            off ^= (cx & 3) << 4;
            *(unsigned int*)((char*)tile + off) = pack;
        }
        __syncthreads();
        #pragma unroll 1
        for (int kx = 0; kx < 5; ++kx) {
            short8 af[5][2];
            #pragma unroll
            for (int ky = 0; ky < 5; ++ky)
                #pragma unroll
                for (int m = 0; m < 2; ++m)
                    af[ky][m] = *(const short8*)(wt + (ky * 5 + kx) * 2048 +
                                                 ((ks * 4 + lg) * 32 + m * 16 + lx) * 8);
            const int key = ((kx + lx) & 3) << 4;
            #pragma unroll
            for (int colf = 0; colf < 2; ++colf) {
                const int cbase = ((2 * w) * 36 + kx + colf * 16 + lx) * 64 + lg * 16;
                short8 bc[6];
                #pragma unroll
                for (int ir = 0; ir < 6; ++ir)
                    bc[ir] = *(const short8*)((char*)tile + ((cbase + ir * (36 * 64)) ^ key));
                #pragma unroll
                for (int ky = 0; ky < 5; ++ky)
                    #pragma unroll
                    for (int q = 0; q < 2; ++q)
                        #pragma unroll
                        for (int m = 0; m < 2; ++m)
                            acc[m][q][colf] = __builtin_amdgcn_mfma_f32_16x16x32_bf16(
                                af[ky][m], bc[q + ky], acc[m][q][colf], 0, 0, 0);
            }
        }
    }

    #pragma unroll
    for (int m = 0; m < 2; ++m)
        #pragma unroll
        for (int q = 0; q < 2; ++q)
            #pragma unroll
            for (int colf = 0; colf < 2; ++colf) {
                int yl = 2 * w + q, x = colf * 16 + lx;
                #pragma unroll
                for (int r = 0; r < 4; ++r) {
                    int och = m * 16 + lg * 4 + r;
                    float v = fmaxf(acc[m][q][colf][r] + b2[och], 0.f);
                    feat[(n * 32 + och) * 1024 + (y0 + yl) * 32 + x] = v;
                }
            }
}

// ---------------- conv3: A from global, B row-cached; optional fused a2-dot ----------------
template<int I, int O, int ACT, int INBF, int OUTBF, int FUSEA2>
__global__ __launch_bounds__(256) void conv3_kernel(
        const void* __restrict__ in_, const short* __restrict__ wt,
        const float* __restrict__ bias, void* __restrict__ out_,
        const float* __restrict__ a2w, float* __restrict__ s9) {
    constexpr int XC = 34, ROWS = 10, KS = I / 32, MF = O / 16, IH = I / 2;
    constexpr int TILE = ROWS * XC * I;
    constexpr int SMSZ = (FUSEA2 && TILE < 16384) ? 16384 : TILE;
    constexpr int ABUF = KS * 4 * O * 8;
    __shared__ __align__(16) short smem[SMSZ];
    __shared__ float wl[FUSEA2 ? 576 : 1];
    const int n = blockIdx.x, y0 = blockIdx.y * 8;
    const int tid = threadIdx.x, w = tid >> 6, l = tid & 63;
    const int lx = l & 15, lg = l >> 4;

    if constexpr (FUSEA2)
        for (int e = tid; e < 576; e += 256) wl[e] = a2w[e];

    for (int e = tid; e < ROWS * XC * IH; e += 256) {
        int cx = e % XC;
        int q = e / XC;
        int ip = q % IH;
        int r = q / IH;
        int gy = y0 - 1 + r, gx = cx - 1;
        unsigned int pack = 0u;
        if (gy >= 0 && gy < 32 && gx >= 0 && gx < 32) {
            if constexpr (INBF) {
                const unsigned short* p =
                    (const unsigned short*)in_ + (n * I + 2 * ip) * 1024 + gy * 32 + gx;
                pack = (unsigned int)p[0] | ((unsigned int)p[1024] << 16);
            } else {
                const float* p = (const float*)in_ + (n * I + 2 * ip) * 1024 + gy * 32 + gx;
                pack = cvt2(p[0], p[1024]);
            }
        }
        int off = ((r * XC + cx) * I + 2 * ip) * 2;
        off ^= (cx & 7) << 4;
        *(unsigned int*)((char*)smem + off) = pack;
    }
    __syncthreads();

    f32x4 acc[MF][2][2];
    #pragma unroll
    for (int m = 0; m < MF; ++m)
        #pragma unroll
        for (int q = 0; q < 2; ++q)
            #pragma unroll
            for (int c = 0; c < 2; ++c) acc[m][q][c] = (f32x4){0.f, 0.f, 0.f, 0.f};

    #pragma unroll 1
    for (int ks = 0; ks < KS; ++ks) {
        #pragma unroll 1
        for (int kx = 0; kx < 3; ++kx) {
            short8 af[3][MF];
            #pragma unroll
            for (int ky = 0; ky < 3; ++ky)
                #pragma unroll
                for (int m = 0; m < MF; ++m)
                    af[ky][m] = *(const short8*)(wt + (ky * 3 + kx) * ABUF +
                                                 ((ks * 4 + lg) * O + m * 16 + lx) * 8);
            const int key = ((kx + lx) & 7) << 4;
            #pragma unroll
            for (int colf = 0; colf < 2; ++colf) {
                const int cbase = ((2 * w) * XC + kx + colf * 16 + lx) * (I * 2)
                                + (ks * 32 + lg * 8) * 2;
                short8 bc[4];
                #pragma unroll
                for (int ir = 0; ir < 4; ++ir)
                    bc[ir] = *(const short8*)((char*)smem + ((cbase + ir * (XC * I * 2)) ^ key));
                #pragma unroll
                for (int ky = 0; ky < 3; ++ky)
                    #pragma unroll
                    for (int q = 0; q < 2; ++q)
                        #pragma unroll
                        for (int m = 0; m < MF; ++m)
                            acc[m][q][colf] = __builtin_amdgcn_mfma_f32_16x16x32_bf16(
                                af[ky][m], bc[q + ky], acc[m][q][colf], 0, 0, 0);
            }
        }
    }

    if constexpr (!FUSEA2) {
        #pragma unroll
        for (int m = 0; m < MF; ++m)
            #pragma unroll
            for (int q = 0; q < 2; ++q)
                #pragma unroll
                for (int colf = 0; colf < 2; ++colf) {
                    int yl = 2 * w + q, x = colf * 16 + lx;
                    #pragma unroll
                    for (int r = 0; r < 4; ++r) {
                        int och = m * 16 + lg * 4 + r;
                        float v = acc[m][q][colf][r] + bias[och];
                        if (ACT == 1) v = v / (1.f + expf(-v));
                        int oidx = (n * O + och) * 1024 + (y0 + yl) * 32 + x;
                        if constexpr (OUTBF)
                            ((unsigned short*)out_)[oidx] = (unsigned short)f2bfu(v);
                        else
                            ((float*)out_)[oidx] = v;
                    }
                }
    } else {
        __syncthreads();
        #pragma unroll
        for (int m = 0; m < MF; ++m)
            #pragma unroll
            for (int q = 0; q < 2; ++q)
                #pragma unroll
                for (int colf = 0; colf < 2; ++colf) {
                    int px_lin = (2 * w + q) * 32 + colf * 16 + lx;
                    unsigned long long pk = 0ull;
                    #pragma unroll
                    for (int r = 0; r < 4; ++r) {
                        int och = m * 16 + lg * 4 + r;
                        float v = acc[m][q][colf][r] + bias[och];
                        v = v / (1.f + expf(-v));
                        pk |= (unsigned long long)f2bfu(v) << (16 * r);
                    }
                    int off = (px_lin * 64 + m * 16 + lg * 4) * 2;
                    off ^= (px_lin & 7) << 4;
                    *(unsigned long long*)((char*)smem + off) = pk;
                }
        __syncthreads();
        float a1v[64];
        {
            const int key2 = (tid & 7) << 4;
            #pragma unroll
            for (int c = 0; c < 8; ++c) {
                short8 v = *(const short8*)((char*)smem + (((tid * 64 + c * 8) * 2) ^ key2));
                #pragma unroll
                for (int j = 0; j < 8; ++j) a1v[c * 8 + j] = bf2f((unsigned short)v[j]);
            }
        }
        int rr = tid >> 5, x = tid & 31;
        #pragma unroll 1
        for (int tap = 0; tap < 9; ++tap) {
            float s = 0.f;
            #pragma unroll
            for (int ch = 0; ch < 64; ++ch) s = fmaf(a1v[ch], wl[ch * 9 + tap], s);
            s9[(tap << 18) + (n << 10) + (y0 + rr) * 32 + x] = s;
        }
    }
}

// ---------------- a2 tap-sum + slot softmax ----------------
__global__ void a2soft_kernel(const float* __restrict__ s9, const float* __restrict__ b2,
                              float* __restrict__ outp) {
    int idx = blockIdx.x * 256 + threadIdx.x;
    if (idx >= 32 * 1024) return;
    int bb = idx >> 10, yx = idx & 1023;
    int y = yx >> 5, x = yx & 31;
    float v[8];
    float bias = b2[0];
    #pragma unroll
    for (int s = 0; s < 8; ++s) {
        int n = bb * 8 + s;
        float a = bias;
        #pragma unroll
        for (int ky = 0; ky < 3; ++ky) {
            int yy = y + ky - 1;
            if (yy < 0 || yy > 31) continue;
            #pragma unroll
            for (int kx = 0; kx < 3; ++kx) {
                int xx = x + kx - 1;
                if (xx < 0 || xx > 31) continue;
                a += s9[((ky * 3 + kx) << 18) + (n << 10) + yy * 32 + xx];
            }
        }
        v[s] = a;
    }
    float m = -3.4e38f;
    #pragma unroll
    for (int s = 0; s < 8; ++s) m = fmaxf(m, v[s]);
    float sum = 0.f;
    #pragma unroll
    for (int s = 0; s < 8; ++s) { v[s] = expf(v[s] - m); sum += v[s]; }
    float inv = 1.f / sum;
    #pragma unroll
    for (int s = 0; s < 8; ++s) outp[AOFF + ((bb * 8 + s) << 10) + yx] = v[s] * inv;
}

// ---------------- VQ via MFMA: S = F . C^T, argmin(cn - 2S) ----------------
// block = 256 threads (4 waves), 256 pixels of one image quarter.
__global__ __launch_bounds__(256) void vq_mfma_kernel(
        const float* __restrict__ feat, const float* __restrict__ codebook,
        unsigned short* __restrict__ qfeat, float* __restrict__ partial) {
    __shared__ float cbf[4096];          // fp32 codebook [128][32]
    __shared__ __align__(16) short cbh[4096];  // bf16 codebook, swizzled
    __shared__ float cn[128];
    __shared__ float red[4];
    const int tid = threadIdx.x;
    const int w = tid >> 6, l = tid & 63;
    const int lx = l & 15, lg = l >> 4;

    for (int e = tid; e < 4096; e += 256) {
        float v = codebook[e];
        cbf[e] = v;
        int code = e >> 5, d = e & 31;
        int off = (code * 32 + d) * 2;
        off ^= (code & 7) << 4;
        *(short*)((char*)cbh + off) = (short)f2bfu(v);
    }
    __syncthreads();
    if (tid < 128) {
        float s = 0.f;
        #pragma unroll
        for (int c = 0; c < 32; ++c) { float v = cbf[tid * 32 + c]; s = fmaf(v, v, s); }
        cn[tid] = s;
    }
    // A-frags: codes m*16+lx, dims lg*8..+7
    short8 af[8];
    #pragma unroll
    for (int m = 0; m < 8; ++m) {
        int code = m * 16 + lx;
        int off = (code * 32 + lg * 8) * 2;
        off ^= (code & 7) << 4;
        af[m] = *(const short8*)((char*)cbh + off);
    }
    __syncthreads();
    // per-lane cn*0.5 for its 32 codes (m*16 + lg*4 + r)
    float cnh[8][4];
    #pragma unroll
    for (int m = 0; m < 8; ++m)
        #pragma unroll
        for (int r = 0; r < 4; ++r)
            cnh[m][r] = 0.5f * cn[m * 16 + lg * 4 + r];

    const int n = blockIdx.x >> 2;
    const int yxw = (blockIdx.x & 3) * 256 + w * 64;
    const float* fb = feat + n * 32768;
    float lloss = 0.f;

    #pragma unroll 1
    for (int pxg = 0; pxg < 4; ++pxg) {
        int yx = yxw + pxg * 16 + lx;
        const float* fp = fb + (lg * 8) * 1024 + yx;
        union { short8 s; unsigned int u[4]; } bb;
        bb.u[0] = cvt2(fp[0],    fp[1024]);
        bb.u[1] = cvt2(fp[2048], fp[3072]);
        bb.u[2] = cvt2(fp[4096], fp[5120]);
        bb.u[3] = cvt2(fp[6144], fp[7168]);
        f32x4 S[8];
        #pragma unroll
        for (int m = 0; m < 8; ++m)
            S[m] = __builtin_amdgcn_mfma_f32_16x16x32_bf16(
                af[m], bb.s, (f32x4){0.f, 0.f, 0.f, 0.f}, 0, 0, 0);
        // argmax of (S - cn/2) == argmin dist, over this lane's 32 codes
        float bestv = -3.4e38f; int besti = 0;
        #pragma unroll
        for (int m = 0; m < 8; ++m)
            #pragma unroll
            for (int r = 0; r < 4; ++r) {
                float v = S[m][r] - cnh[m][r];
                int code = m * 16 + lg * 4 + r;
                if (v > bestv) { bestv = v; besti = code; }
            }
        // combine across the 4 lanes (lg) holding this pixel
        #pragma unroll
        for (int d = 16; d < 64; d <<= 1) {
            float ov = __shfl_xor(bestv, d);
            int oi = __shfl_xor(besti, d);
            if (ov > bestv || (ov == bestv && oi < besti)) { bestv = ov; besti = oi; }
        }
        // write q (bf16) for this lane's 8 dims + loss partial
        int offq = (besti * 32 + lg * 8) * 2;
        offq ^= (besti & 7) << 4;
        short8 qh = *(const short8*)((char*)cbh + offq);
        unsigned short* qp = qfeat + (n * 32 + lg * 8) * 1024 + yx;
        const float* qf = &cbf[besti * 32 + lg * 8];
        #pragma unroll
        for (int j = 0; j < 8; ++j) {
            qp[j * 1024] = (unsigned short)qh[j];
            float fv = bf2f((unsigned short)bb.s[j]);
            float dd = qf[j] - fv;
            lloss = fmaf(dd, dd, lloss);
        }
    }
    for (int off = 32; off > 0; off >>= 1) lloss += __shfl_down(lloss, off);
    if (l == 0) red[w] = lloss;
    __syncthreads();
    if (tid == 0) partial[blockIdx.x] = (red[0] + red[1]) + (red[2] + red[3]);
}

__global__ void recon_kernel(const unsigned short* __restrict__ colors, float* __restrict__ outp) {
    int idx = blockIdx.x * 256 + threadIdx.x;
    int yx = idx & 1023;
    int v = (idx >> 10) & 63;
    int bb = idx >> 16;
    float acc = 0.f;
    #pragma unroll
    for (int s = 0; s < 8; ++s) {
        float a = outp[AOFF + ((bb * 8 + s) << 10) + yx];
        float c = bf2f(colors[((bb * 8 + s) * 64 + v) * 1024 + yx]);
        acc = fmaf(a, c, acc);
    }
    outp[idx] = acc;
}

__global__ void loss_kernel(const float* __restrict__ partial, float* __restrict__ outp) {
    __shared__ float red[4];
    int t = threadIdx.x;
    float s = 0.f;
    for (int i = t; i < 1024; i += 256) s += partial[i];
    for (int o = 32; o > 0; o >>= 1) s += __shfl_down(s, o);
    if ((t & 63) == 0) red[t >> 6] = s;
    __syncthreads();
    if (t == 0) outp[LOFF] = 1.25f * ((red[0] + red[1]) + (red[2] + red[3])) / 8388608.0f;
}

extern "C" void kernel_launch(void* const* d_in, const int* in_sizes, int n_in,
                              void* d_out, int out_size, void* d_ws, size_t ws_size,
                              hipStream_t stream) {
    const float* latent  = (const float*)d_in[0];
    const float* pos_w   = (const float*)d_in[1];
    const float* pos_b   = (const float*)d_in[2];
    const float* ct1_w   = (const float*)d_in[3];
    const float* ct1_b   = (const float*)d_in[4];
    const float* ct2_w   = (const float*)d_in[5];
    const float* ct2_b   = (const float*)d_in[6];
    const float* codebook= (const float*)d_in[7];
    const float* c1_w    = (const float*)d_in[8];
    const float* c1_b    = (const float*)d_in[9];
    const float* c2_w    = (const float*)d_in[10];
    const float* c2_b    = (const float*)d_in[11];
    const float* a1_w    = (const float*)d_in[12];
    const float* a1_b    = (const float*)d_in[13];
    const float* a2_w    = (const float*)d_in[14];
    const float* a2_b    = (const float*)d_in[15];
    float* out = (float*)d_out;

    float* ws     = (float*)d_ws;
    float* feat   = ws;                      // 8388608
    float* s9     = feat + 8388608;          // 2359296
    float* tapabc = s9 + 2359296;            // 4800
    float* P      = tapabc + 4800;           // 65536 (pair-interleaved float2 layout)
    float* M      = P + 65536;               // 409600
    float* partial= M + 409600;              // 1024
    float* w1t    = partial + 1024;          // 204800
    float* Wsum   = w1t + 204800;            // 204800
    short* wtall  = (short*)(Wsum + 204800); // 124928 shorts
    short* wtA    = wtall;
    short* wtC1   = wtall + 18432;
    short* wtC2   = wtall + 36864;
    short* wtT2   = wtall + 73728;
    unsigned short* tmpb    = (unsigned short*)(wtall + 124928);  // 16777216
    unsigned short* qfeatb  = tmpb + 16777216;                    // 8388608
    unsigned short* colorsb = qfeatb + 8388608;                   // 16777216

    w1t_kernel<<<800, 256, 0, stream>>>(ct1_w, w1t);
    tapabc_kernel<<<25, 192, 0, stream>>>(pos_w, pos_b, w1t, tapabc);
    pfill_kernel<<<64, 1024, 0, stream>>>(tapabc, ct1_b, P);
    wsum_kernel<<<800, 256, 0, stream>>>(ct1_w, Wsum);
    m_kernel<<<dim3(256, 25), 64, 0, stream>>>(latent, Wsum, M);
    prep_all_kernel<<<488, 256, 0, stream>>>(a1_w, c1_w, c2_w, ct2_w, wtall);

    conv5_kernel<<<dim3(256, 4), 256, 0, stream>>>(M, P, wtT2, ct2_b, feat);
    // alpha head: a1 conv with fused a2 channel-dot -> s9 -> softmax
    conv3_kernel<32, 64, 1, 0, 0, 1><<<dim3(256, 4), 256, 0, stream>>>(
        feat, wtA, a1_b, nullptr, a2_w, s9);
    a2soft_kernel<<<128, 256, 0, stream>>>(s9, a2_b, out);
    // VQ (MFMA)
    vq_mfma_kernel<<<1024, 256, 0, stream>>>(feat, codebook, qfeatb, partial);
    // color head
    conv3_kernel<32, 64, 1, 1, 1, 0><<<dim3(256, 4), 256, 0, stream>>>(
        qfeatb, wtC1, c1_b, tmpb, nullptr, nullptr);
    conv3_kernel<64, 64, 0, 1, 1, 0><<<dim3(256, 4), 256, 0, stream>>>(
        tmpb, wtC2, c2_b, colorsb, nullptr, nullptr);
    recon_kernel<<<8192, 256, 0, stream>>>(colorsb, out);
    loss_kernel<<<1, 256, 0, stream>>>(partial, out);
}

// Round 9
// 261.424 us; speedup vs baseline: 1.5832x; 1.0007x over previous
//
#include <hip/hip_runtime.h>
#include <math.h>

#define AOFF 2097152   // recon = 32*64*1024 floats, alphas follow
#define LOFF 2359296   // AOFF + 32*8*1024

typedef __attribute__((ext_vector_type(8))) short short8;
typedef __attribute__((ext_vector_type(4))) float f32x4;

__device__ __forceinline__ int clsf(int v) { return v < 2 ? v : (v > 29 ? v - 27 : 2); }

__device__ __forceinline__ unsigned int f2bfu(float x) {
    unsigned int u = __float_as_uint(x);
    return (u + 0x7FFFu + ((u >> 16) & 1u)) >> 16;
}
__device__ __forceinline__ unsigned int cvt2(float a, float b) {
    return f2bfu(a) | (f2bfu(b) << 16);
}
__device__ __forceinline__ float bf2f(unsigned short u) {
    return __uint_as_float(((unsigned int)u) << 16);
}

// ---------------- w1 transpose: w1t[tap][i][o] ----------------
__global__ void w1t_kernel(const float* __restrict__ w1, float* __restrict__ w1t) {
    int idx = blockIdx.x * 256 + threadIdx.x;
    if (idx >= 204800) return;
    int tap = idx % 25, rest = idx / 25;       // rest = i*64+o
    w1t[tap * 8192 + rest] = w1[idx];
}

// ---------------- tapabc: per-tap dot with affine pos coeffs ----------------
__global__ void tapabc_kernel(const float* __restrict__ pw, const float* __restrict__ pb,
                              const float* __restrict__ w1t, float* __restrict__ tapabc) {
    __shared__ float A3[384];
    int tap = blockIdx.x, t = threadIdx.x;     // 192 threads
    if (t < 128) {
        float p0 = pw[t * 4], p1 = pw[t * 4 + 1], p2 = pw[t * 4 + 2], p3 = pw[t * 4 + 3];
        A3[t] = p2 + p3 + pb[t];
        A3[128 + t] = p0 - p2;
        A3[256 + t] = p1 - p3;
    }
    __syncthreads();
    int o = t & 63, comp = t >> 6;
    const float* wp = w1t + tap * 8192 + o;
    const float* a = A3 + comp * 128;
    float s = 0.f;
    for (int i = 0; i < 128; ++i) s = fmaf(wp[i * 64], a[i], s);
    tapabc[(tap * 64 + o) * 3 + comp] = s;
}

// ---------------- P fill: channel-PAIR interleaved float2 layout ----------------
__global__ void pfill_kernel(const float* __restrict__ tapabc, const float* __restrict__ b1,
                             float* __restrict__ P2) {
    __shared__ float uv[75];
    int o = blockIdx.x, t = threadIdx.x;       // 1024 threads
    if (t < 75) {
        int cls = t / 3, comp = t % 3;
        int cy = cls / 5, cx = cls % 5;
        const int klo[5] = {2, 1, 0, 0, 0}, khi[5] = {4, 4, 4, 3, 2};
        const float inv31 = 1.f / 31.f;
        float s = (comp == 0) ? b1[o] : 0.f;
        for (int ky = klo[cy]; ky <= khi[cy]; ++ky)
            for (int kx = klo[cx]; kx <= khi[cx]; ++kx) {
                int tap = (4 - ky) * 5 + (4 - kx);
                const float* tp = &tapabc[(tap * 64 + o) * 3];
                if (comp == 0) s += tp[0] + tp[1] * (ky - 2) * inv31 + tp[2] * (kx - 2) * inv31;
                else if (comp == 1) s += tp[1] * inv31;
                else s += tp[2] * inv31;
            }
        uv[t] = s;
    }
    __syncthreads();
    int y = t >> 5, x = t & 31;
    int cls = clsf(y) * 5 + clsf(x);
    float val = uv[cls * 3] + uv[cls * 3 + 1] * y + uv[cls * 3 + 2] * x;
    P2[((o >> 1) << 11) + (t << 1) + (o & 1)] = val;
}

// ---------------- Wsum[cls][i][o] ----------------
__global__ void wsum_kernel(const float* __restrict__ w1, float* __restrict__ Wsum) {
    int idx = blockIdx.x * 256 + threadIdx.x;
    if (idx >= 25 * 128 * 64) return;
    int cls = idx >> 13;
    int i = (idx >> 6) & 127;
    int o = idx & 63;
    int cy = cls / 5, cx = cls % 5;
    const int klo[5] = {2, 1, 0, 0, 0}, khi[5] = {4, 4, 4, 3, 2};
    float s = 0.f;
    for (int ky = klo[cy]; ky <= khi[cy]; ++ky)
        for (int kx = klo[cx]; kx <= khi[cx]; ++kx)
            s += w1[(i * 64 + o) * 25 + (4 - ky) * 5 + (4 - kx)];
    Wsum[idx] = s;
}

// ---------------- M[n][cls][o] = latent[n,:] . Wsum[cls,:,o] ----------------
__global__ void m_kernel(const float* __restrict__ latent, const float* __restrict__ Wsum,
                         float* __restrict__ M) {
    int n = blockIdx.x, cls = blockIdx.y, o = threadIdx.x;
    const float* l = &latent[n * 128];
    const float* w = &Wsum[cls * 8192 + o];
    float a0 = 0.f, a1 = 0.f;
    for (int i = 0; i < 128; i += 2) {
        a0 = fmaf(l[i], w[i * 64], a0);
        a1 = fmaf(l[i + 1], w[(i + 1) * 64], a1);
    }
    M[(n * 25 + cls) * 64 + o] = a0 + a1;
}

// ---------------- merged weight prep (4 segments) ----------------
__global__ void prep_all_kernel(const float* __restrict__ a1w, const float* __restrict__ c1w,
                                const float* __restrict__ c2w, const float* __restrict__ ct2w,
                                short* __restrict__ wtall) {
    int gid = blockIdx.x * 256 + threadIdx.x;
    if (gid < 36864) {                                  // a1 / c1 : I=32,O=64
        const float* src = gid < 18432 ? a1w : c1w;
        int idx = gid < 18432 ? gid : gid - 18432;
        int j = idx & 7, fi = idx >> 3;
        int o = fi % 64, g = (fi / 64) & 3, t = fi / 256;
        int i = g * 8 + j;
        wtall[gid] = (short)f2bfu(src[(o * 32 + i) * 9 + (t / 3) * 3 + (t % 3)]);
    } else if (gid < 73728) {                           // c2 : I=64,O=64
        int idx = gid - 36864;
        int j = idx & 7, fi = idx >> 3;
        int o = fi % 64, g = (fi / 64) & 3, ks = (fi / 256) & 1, t = fi / 512;
        int i = ks * 32 + g * 8 + j;
        wtall[gid] = (short)f2bfu(c2w[(o * 64 + i) * 9 + (t / 3) * 3 + (t % 3)]);
    } else if (gid < 124928) {                          // convT2 : flipped 5x5
        int idx = gid - 73728;
        int j = idx & 7, fi = idx >> 3;
        int o = fi & 31, g = (fi >> 5) & 3, ks = (fi >> 7) & 1, t = fi >> 8;
        int i = ks * 32 + g * 8 + j;
        int ky = t / 5, kx = t % 5;
        wtall[gid] = (short)f2bfu(ct2w[((i * 32 + o) * 5 + (4 - ky)) * 5 + (4 - kx)]);
    }
}

// ---------------- conv5 (convT2): split-K staging, bf16 output ----------------
__global__ __launch_bounds__(256, 4) void conv5_kernel(
        const float* __restrict__ M, const float* __restrict__ P2,
        const short* __restrict__ wt, const float* __restrict__ b2,
        unsigned short* __restrict__ featb) {
    __shared__ __align__(16) short tile[12 * 36 * 32];  // 27648 B
    __shared__ float Ml[1600];                          // 6400 B
    const int n = blockIdx.x, y0 = blockIdx.y * 8;
    const int tid = threadIdx.x, w = tid >> 6, l = tid & 63;
    const int lx = l & 15, lg = l >> 4;

    for (int e = tid; e < 1600; e += 256) Ml[e] = M[n * 1600 + e];
    __syncthreads();

    f32x4 acc[2][2][2];
    #pragma unroll
    for (int m = 0; m < 2; ++m)
        #pragma unroll
        for (int q = 0; q < 2; ++q)
            #pragma unroll
            for (int c = 0; c < 2; ++c) acc[m][q][c] = (f32x4){0.f, 0.f, 0.f, 0.f};

    #pragma unroll 1
    for (int ks = 0; ks < 2; ++ks) {
        if (ks) __syncthreads();
        for (int e = tid; e < 6912; e += 256) {
            int cx = e % 36;
            int q = e / 36;
            int ipl = q & 15;
            int r = q >> 4;
            int gy = y0 - 2 + r, gx = cx - 2;
            unsigned int pack = 0u;
            if (gy >= 0 && gy < 32 && gx >= 0 && gx < 32) {
                int cls = clsf(gy) * 5 + clsf(gx);
                int pp = gy * 32 + gx;
                float2 pv = ((const float2*)P2)[((ks * 16 + ipl) << 10) + pp];
                float2 ml = ((const float2*)Ml)[cls * 32 + ks * 16 + ipl];
                pack = cvt2(fmaxf(ml.x + pv.x, 0.f), fmaxf(ml.y + pv.y, 0.f));
            }
            int off = ((r * 36 + cx) * 32 + 2 * ipl) * 2;
            off ^= (cx & 3) << 4;
            *(unsigned int*)((char*)tile + off) = pack;
        }
        __syncthreads();
        #pragma unroll 1
        for (int kx = 0; kx < 5; ++kx) {
            short8 af[5][2];
            #pragma unroll
            for (int ky = 0; ky < 5; ++ky)
                #pragma unroll
                for (int m = 0; m < 2; ++m)
                    af[ky][m] = *(const short8*)(wt + (ky * 5 + kx) * 2048 +
                                                 ((ks * 4 + lg) * 32 + m * 16 + lx) * 8);
            const int key = ((kx + lx) & 3) << 4;
            #pragma unroll
            for (int colf = 0; colf < 2; ++colf) {
                const int cbase = ((2 * w) * 36 + kx + colf * 16 + lx) * 64 + lg * 16;
                short8 bc[6];
                #pragma unroll
                for (int ir = 0; ir < 6; ++ir)
                    bc[ir] = *(const short8*)((char*)tile + ((cbase + ir * (36 * 64)) ^ key));
                #pragma unroll
                for (int ky = 0; ky < 5; ++ky)
                    #pragma unroll
                    for (int q = 0; q < 2; ++q)
                        #pragma unroll
                        for (int m = 0; m < 2; ++m)
                            acc[m][q][colf] = __builtin_amdgcn_mfma_f32_16x16x32_bf16(
                                af[ky][m], bc[q + ky], acc[m][q][colf], 0, 0, 0);
            }
        }
    }

    #pragma unroll
    for (int m = 0; m < 2; ++m)
        #pragma unroll
        for (int q = 0; q < 2; ++q)
            #pragma unroll
            for (int colf = 0; colf < 2; ++colf) {
                int yl = 2 * w + q, x = colf * 16 + lx;
                #pragma unroll
                for (int r = 0; r < 4; ++r) {
                    int och = m * 16 + lg * 4 + r;
                    float v = fmaxf(acc[m][q][colf][r] + b2[och], 0.f);
                    featb[(n * 32 + och) * 1024 + (y0 + yl) * 32 + x] = (unsigned short)f2bfu(v);
                }
            }
}

// ---------------- conv3: split-K staging (tile fixed at 32 ch), bf16 in/out ----------------
template<int I, int O, int ACT>
__global__ __launch_bounds__(256) void conv3_kernel(
        const unsigned short* __restrict__ in_, const short* __restrict__ wt,
        const float* __restrict__ bias, unsigned short* __restrict__ out_) {
    constexpr int KS = I / 32, MF = O / 16;
    constexpr int ABUF = KS * 4 * O * 8;
    __shared__ __align__(16) short smem[10 * 34 * 32];   // 21760 B
    const int n = blockIdx.x, y0 = blockIdx.y * 8;
    const int tid = threadIdx.x, w = tid >> 6, l = tid & 63;
    const int lx = l & 15, lg = l >> 4;

    f32x4 acc[MF][2][2];
    #pragma unroll
    for (int m = 0; m < MF; ++m)
        #pragma unroll
        for (int q = 0; q < 2; ++q)
            #pragma unroll
            for (int c = 0; c < 2; ++c) acc[m][q][c] = (f32x4){0.f, 0.f, 0.f, 0.f};

    #pragma unroll 1
    for (int ks = 0; ks < KS; ++ks) {
        if (ks) __syncthreads();
        for (int e = tid; e < 5440; e += 256) {
            int cx = e % 34;
            int q = e / 34;
            int ip = q & 15;
            int r = q >> 4;
            int gy = y0 - 1 + r, gx = cx - 1;
            unsigned int pack = 0u;
            if (gy >= 0 && gy < 32 && gx >= 0 && gx < 32) {
                const unsigned short* p =
                    in_ + (n * I + ks * 32 + 2 * ip) * 1024 + gy * 32 + gx;
                pack = (unsigned int)p[0] | ((unsigned int)p[1024] << 16);
            }
            int off = ((r * 34 + cx) * 32 + 2 * ip) * 2;
            off ^= (cx & 7) << 4;
            *(unsigned int*)((char*)smem + off) = pack;
        }
        __syncthreads();
        #pragma unroll 1
        for (int kx = 0; kx < 3; ++kx) {
            short8 af[3][MF];
            #pragma unroll
            for (int ky = 0; ky < 3; ++ky)
                #pragma unroll
                for (int m = 0; m < MF; ++m)
                    af[ky][m] = *(const short8*)(wt + (ky * 3 + kx) * ABUF +
                                                 ((ks * 4 + lg) * O + m * 16 + lx) * 8);
            const int key = ((kx + lx) & 7) << 4;
            #pragma unroll
            for (int colf = 0; colf < 2; ++colf) {
                const int cbase = ((2 * w) * 34 + kx + colf * 16 + lx) * 64 + lg * 16;
                short8 bc[4];
                #pragma unroll
                for (int ir = 0; ir < 4; ++ir)
                    bc[ir] = *(const short8*)((char*)smem + ((cbase + ir * (34 * 64)) ^ key));
                #pragma unroll
                for (int ky = 0; ky < 3; ++ky)
                    #pragma unroll
                    for (int q = 0; q < 2; ++q)
                        #pragma unroll
                        for (int m = 0; m < MF; ++m)
                            acc[m][q][colf] = __builtin_amdgcn_mfma_f32_16x16x32_bf16(
                                af[ky][m], bc[q + ky], acc[m][q][colf], 0, 0, 0);
            }
        }
    }

    #pragma unroll
    for (int m = 0; m < MF; ++m)
        #pragma unroll
        for (int q = 0; q < 2; ++q)
            #pragma unroll
            for (int colf = 0; colf < 2; ++colf) {
                int yl = 2 * w + q, x = colf * 16 + lx;
                #pragma unroll
                for (int r = 0; r < 4; ++r) {
                    int och = m * 16 + lg * 4 + r;
                    float v = acc[m][q][colf][r] + bias[och];
                    if (ACT == 1) v = v / (1.f + expf(-v));
                    out_[(n * O + och) * 1024 + (y0 + yl) * 32 + x] = (unsigned short)f2bfu(v);
                }
            }
}

// ---------------- a2 channel-dot: s9[tap][n*1024+p] = sum_i a1out * a2w ----------------
__global__ void a2dot_kernel(const unsigned short* __restrict__ in, const float* __restrict__ w,
                             float* __restrict__ s9) {
    __shared__ float wl[576];
    int t = threadIdx.x;
    for (int e = t; e < 576; e += 256) wl[e] = w[e];
    __syncthreads();
    int p = blockIdx.x * 256 + t;        // 262144 total
    int n = p >> 10, yx = p & 1023;
    float acc[9];
    #pragma unroll
    for (int k = 0; k < 9; ++k) acc[k] = 0.f;
    const unsigned short* ip = in + n * 65536 + yx;
    for (int i = 0; i < 64; ++i) {
        float v = bf2f(ip[i * 1024]);
        #pragma unroll
        for (int k = 0; k < 9; ++k) acc[k] = fmaf(v, wl[i * 9 + k], acc[k]);
    }
    #pragma unroll
    for (int k = 0; k < 9; ++k) s9[(k << 18) + p] = acc[k];
}

// ---------------- a2 tap-sum + slot softmax ----------------
__global__ void a2soft_kernel(const float* __restrict__ s9, const float* __restrict__ b2,
                              float* __restrict__ outp) {
    int idx = blockIdx.x * 256 + threadIdx.x;
    if (idx >= 32 * 1024) return;
    int bb = idx >> 10, yx = idx & 1023;
    int y = yx >> 5, x = yx & 31;
    float v[8];
    float bias = b2[0];
    #pragma unroll
    for (int s = 0; s < 8; ++s) {
        int n = bb * 8 + s;
        float a = bias;
        #pragma unroll
        for (int ky = 0; ky < 3; ++ky) {
            int yy = y + ky - 1;
            if (yy < 0 || yy > 31) continue;
            #pragma unroll
            for (int kx = 0; kx < 3; ++kx) {
                int xx = x + kx - 1;
                if (xx < 0 || xx > 31) continue;
                a += s9[((ky * 3 + kx) << 18) + (n << 10) + yy * 32 + xx];
            }
        }
        v[s] = a;
    }
    float m = -3.4e38f;
    #pragma unroll
    for (int s = 0; s < 8; ++s) m = fmaxf(m, v[s]);
    float sum = 0.f;
    #pragma unroll
    for (int s = 0; s < 8; ++s) { v[s] = expf(v[s] - m); sum += v[s]; }
    float inv = 1.f / sum;
    #pragma unroll
    for (int s = 0; s < 8; ++s) outp[AOFF + ((bb * 8 + s) << 10) + yx] = v[s] * inv;
}

// ---------------- VQ via MFMA (bf16 feat input) ----------------
__global__ __launch_bounds__(256) void vq_mfma_kernel(
        const unsigned short* __restrict__ featb, const float* __restrict__ codebook,
        unsigned short* __restrict__ qfeat, float* __restrict__ partial) {
    __shared__ float cbf[4096];          // fp32 codebook [128][32]
    __shared__ __align__(16) short cbh[4096];  // bf16 codebook, swizzled
    __shared__ float cn[128];
    __shared__ float red[4];
    const int tid = threadIdx.x;
    const int w = tid >> 6, l = tid & 63;
    const int lx = l & 15, lg = l >> 4;

    for (int e = tid; e < 4096; e += 256) {
        float v = codebook[e];
        cbf[e] = v;
        int code = e >> 5, d = e & 31;
        int off = (code * 32 + d) * 2;
        off ^= (code & 7) << 4;
        *(short*)((char*)cbh + off) = (short)f2bfu(v);
    }
    __syncthreads();
    if (tid < 128) {
        float s = 0.f;
        #pragma unroll
        for (int c = 0; c < 32; ++c) { float v = cbf[tid * 32 + c]; s = fmaf(v, v, s); }
        cn[tid] = s;
    }
    short8 af[8];
    #pragma unroll
    for (int m = 0; m < 8; ++m) {
        int code = m * 16 + lx;
        int off = (code * 32 + lg * 8) * 2;
        off ^= (code & 7) << 4;
        af[m] = *(const short8*)((char*)cbh + off);
    }
    __syncthreads();
    float cnh[8][4];
    #pragma unroll
    for (int m = 0; m < 8; ++m)
        #pragma unroll
        for (int r = 0; r < 4; ++r)
            cnh[m][r] = 0.5f * cn[m * 16 + lg * 4 + r];

    const int n = blockIdx.x >> 2;
    const int yxw = (blockIdx.x & 3) * 256 + w * 64;
    const unsigned short* fb = featb + n * 32768;
    float lloss = 0.f;

    #pragma unroll 1
    for (int pxg = 0; pxg < 4; ++pxg) {
        int yx = yxw + pxg * 16 + lx;
        const unsigned short* fp = fb + (lg * 8) * 1024 + yx;
        union { short8 s; unsigned int u[4]; } bb;
        #pragma unroll
        for (int k = 0; k < 4; ++k)
            bb.u[k] = (unsigned int)fp[(2 * k) * 1024] | ((unsigned int)fp[(2 * k + 1) * 1024] << 16);
        f32x4 S[8];
        #pragma unroll
        for (int m = 0; m < 8; ++m)
            S[m] = __builtin_amdgcn_mfma_f32_16x16x32_bf16(
                af[m], bb.s, (f32x4){0.f, 0.f, 0.f, 0.f}, 0, 0, 0);
        float bestv = -3.4e38f; int besti = 0;
        #pragma unroll
        for (int m = 0; m < 8; ++m)
            #pragma unroll
            for (int r = 0; r < 4; ++r) {
                float v = S[m][r] - cnh[m][r];
                int code = m * 16 + lg * 4 + r;
                if (v > bestv) { bestv = v; besti = code; }
            }
        #pragma unroll
        for (int d = 16; d < 64; d <<= 1) {
            float ov = __shfl_xor(bestv, d);
            int oi = __shfl_xor(besti, d);
            if (ov > bestv || (ov == bestv && oi < besti)) { bestv = ov; besti = oi; }
        }
        int offq = (besti * 32 + lg * 8) * 2;
        offq ^= (besti & 7) << 4;
        short8 qh = *(const short8*)((char*)cbh + offq);
        unsigned short* qp = qfeat + (n * 32 + lg * 8) * 1024 + yx;
        const float* qf = &cbf[besti * 32 + lg * 8];
        #pragma unroll
        for (int j = 0; j < 8; ++j) {
            qp[j * 1024] = (unsigned short)qh[j];
            float fv = bf2f((unsigned short)bb.s[j]);
            float dd = qf[j] - fv;
            lloss = fmaf(dd, dd, lloss);
        }
    }
    for (int off = 32; off > 0; off >>= 1) lloss += __shfl_down(lloss, off);
    if (l == 0) red[w] = lloss;
    __syncthreads();
    if (tid == 0) partial[blockIdx.x] = (red[0] + red[1]) + (red[2] + red[3]);
}

__global__ void recon_kernel(const unsigned short* __restrict__ colors, float* __restrict__ outp) {
    int idx = blockIdx.x * 256 + threadIdx.x;
    int yx = idx & 1023;
    int v = (idx >> 10) & 63;
    int bb = idx >> 16;
    float acc = 0.f;
    #pragma unroll
    for (int s = 0; s < 8; ++s) {
        float a = outp[AOFF + ((bb * 8 + s) << 10) + yx];
        float c = bf2f(colors[((bb * 8 + s) * 64 + v) * 1024 + yx]);
        acc = fmaf(a, c, acc);
    }
    outp[idx] = acc;
}

__global__ void loss_kernel(const float* __restrict__ partial, float* __restrict__ outp) {
    __shared__ float red[4];
    int t = threadIdx.x;
    float s = 0.f;
    for (int i = t; i < 1024; i += 256) s += partial[i];
    for (int o = 32; o > 0; o >>= 1) s += __shfl_down(s, o);
    if ((t & 63) == 0) red[t >> 6] = s;
    __syncthreads();
    if (t == 0) outp[LOFF] = 1.25f * ((red[0] + red[1]) + (red[2] + red[3])) / 8388608.0f;
}

extern "C" void kernel_launch(void* const* d_in, const int* in_sizes, int n_in,
                              void* d_out, int out_size, void* d_ws, size_t ws_size,
                              hipStream_t stream) {
    const float* latent  = (const float*)d_in[0];
    const float* pos_w   = (const float*)d_in[1];
    const float* pos_b   = (const float*)d_in[2];
    const float* ct1_w   = (const float*)d_in[3];
    const float* ct1_b   = (const float*)d_in[4];
    const float* ct2_w   = (const float*)d_in[5];
    const float* ct2_b   = (const float*)d_in[6];
    const float* codebook= (const float*)d_in[7];
    const float* c1_w    = (const float*)d_in[8];
    const float* c1_b    = (const float*)d_in[9];
    const float* c2_w    = (const float*)d_in[10];
    const float* c2_b    = (const float*)d_in[11];
    const float* a1_w    = (const float*)d_in[12];
    const float* a1_b    = (const float*)d_in[13];
    const float* a2_w    = (const float*)d_in[14];
    const float* a2_b    = (const float*)d_in[15];
    float* out = (float*)d_out;

    float* ws     = (float*)d_ws;
    unsigned short* featb = (unsigned short*)ws;   // 8388608 ushorts (region of 8388608 floats)
    float* s9     = ws + 8388608;            // 2359296
    float* tapabc = s9 + 2359296;            // 4800
    float* P      = tapabc + 4800;           // 65536 (pair-interleaved float2 layout)
    float* M      = P + 65536;               // 409600
    float* partial= M + 409600;              // 1024
    float* w1t    = partial + 1024;          // 204800
    float* Wsum   = w1t + 204800;            // 204800
    short* wtall  = (short*)(Wsum + 204800); // 124928 shorts
    short* wtA    = wtall;
    short* wtC1   = wtall + 18432;
    short* wtC2   = wtall + 36864;
    short* wtT2   = wtall + 73728;
    unsigned short* tmpb    = (unsigned short*)(wtall + 124928);  // 16777216
    unsigned short* qfeatb  = tmpb + 16777216;                    // 8388608
    unsigned short* colorsb = qfeatb + 8388608;                   // 16777216

    w1t_kernel<<<800, 256, 0, stream>>>(ct1_w, w1t);
    tapabc_kernel<<<25, 192, 0, stream>>>(pos_w, pos_b, w1t, tapabc);
    pfill_kernel<<<64, 1024, 0, stream>>>(tapabc, ct1_b, P);
    wsum_kernel<<<800, 256, 0, stream>>>(ct1_w, Wsum);
    m_kernel<<<dim3(256, 25), 64, 0, stream>>>(latent, Wsum, M);
    prep_all_kernel<<<488, 256, 0, stream>>>(a1_w, c1_w, c2_w, ct2_w, wtall);

    conv5_kernel<<<dim3(256, 4), 256, 0, stream>>>(M, P, wtT2, ct2_b, featb);
    // alpha head: a1 conv (bf16 in/out) -> a2 channel-dot -> tap-sum+softmax
    conv3_kernel<32, 64, 1><<<dim3(256, 4), 256, 0, stream>>>(featb, wtA, a1_b, tmpb);
    a2dot_kernel<<<1024, 256, 0, stream>>>(tmpb, a2_w, s9);
    a2soft_kernel<<<128, 256, 0, stream>>>(s9, a2_b, out);
    // VQ (MFMA, bf16 feat)
    vq_mfma_kernel<<<1024, 256, 0, stream>>>(featb, codebook, qfeatb, partial);
    // color head
    conv3_kernel<32, 64, 1><<<dim3(256, 4), 256, 0, stream>>>(qfeatb, wtC1, c1_b, tmpb);
    conv3_kernel<64, 64, 0><<<dim3(256, 4), 256, 0, stream>>>(tmpb, wtC2, c2_b, colorsb);
    recon_kernel<<<8192, 256, 0, stream>>>(colorsb, out);
    loss_kernel<<<1, 256, 0, stream>>>(partial, out);
}